// Round 21
// baseline (446.173 us; speedup 1.0000x reference)
//
#include <hip/hip_runtime.h>
#include <hip/hip_bf16.h>
#include <cmath>

constexpr int cBS = 8;
constexpr int cNQ = 1000;
constexpr int cNV = 20000;
constexpr int cE  = 256;
constexpr int cHH = 8;
constexpr int cDH = 32;
constexpr int cP  = 4;
constexpr int cFFN = 512;
constexpr int cH = 100;
constexpr int cW = 200;
constexpr int NTOK = cNQ * cBS;   // 8000
constexpr size_t QKSZ2 = (size_t)64 * 1024 * cDH;  // 2,097,152 ushorts per padded bf16 buffer

typedef float f32x4 __attribute__((ext_vector_type(4)));
typedef short bf16x8 __attribute__((ext_vector_type(8)));
union U8 { uint u[4]; bf16x8 v; };

__device__ __forceinline__ void split_bf(float x, ushort& h, ushort& l) {
    __hip_bfloat16 hb = __float2bfloat16(x);
    float hf = __bfloat162float(hb);
    __hip_bfloat16 lb = __float2bfloat16(x - hf);
    h = *reinterpret_cast<ushort*>(&hb);
    l = *reinterpret_cast<ushort*>(&lb);
}
__device__ __forceinline__ void pk_split2(float a, float b, uint& h, uint& l) {
    __hip_bfloat16 ah = __float2bfloat16(a), bh = __float2bfloat16(b);
    float arf = a - __bfloat162float(ah), brf = b - __bfloat162float(bh);
    __hip_bfloat16 al = __float2bfloat16(arf), bl = __float2bfloat16(brf);
    h = ((uint)*reinterpret_cast<ushort*>(&bh) << 16) | *reinterpret_cast<ushort*>(&ah);
    l = ((uint)*reinterpret_cast<ushort*>(&bl) << 16) | *reinterpret_cast<ushort*>(&al);
}

__device__ __forceinline__ void gl_lds16(const float* g, float* l) {
    __builtin_amdgcn_global_load_lds(
        (const __attribute__((address_space(1))) unsigned int*)g,
        (__attribute__((address_space(3))) unsigned int*)l,
        16, 0, 0);
}

__global__ __launch_bounds__(256) void k_zerou4(uint4* __restrict__ p, int n)
{
    int i = blockIdx.x * 256 + threadIdx.x;
    if (i < n) p[i] = uint4{0u, 0u, 0u, 0u};
}

// ---------------------------------------------------------------- weight prep (per-lane fragment layout)
__global__ __launch_bounds__(256) void k_prepw(
    const float* __restrict__ Wsrc, ushort* __restrict__ wpk,
    int nkk /* K/32 */, int total /* N*4*nkk */, int losz /* N*K elems */)
{
    int gid = blockIdx.x * 256 + threadIdx.x;
    if (gid >= total) return;
    int g  = gid & 3;
    int kk = (gid >> 2) % nkk;
    int n  = gid / (4 * nkk);
    const float* src = Wsrc + (size_t)n * (nkk * 32) + kk * 32 + 4 * g;
    float4 x0 = *reinterpret_cast<const float4*>(src);
    float4 x1 = *reinterpret_cast<const float4*>(src + 16);
    float xs[8] = {x0.x, x0.y, x0.z, x0.w, x1.x, x1.y, x1.z, x1.w};
    union { ushort s[8]; uint4 q; } hi_, lo_;
#pragma unroll
    for (int j = 0; j < 8; j++) split_bf(xs[j], hi_.s[j], lo_.s[j]);
    *reinterpret_cast<uint4*>(wpk + (size_t)gid * 8)        = hi_.q;
    *reinterpret_cast<uint4*>(wpk + losz + (size_t)gid * 8) = lo_.q;
}

// ---------------------------------------------------------------- weight prep (wave-contiguous layout, vproj)
// Col permutation for float4 C-writes: slot (nblk, lane=g*16+ln) holds W row
// n = (nblk>>2)*64 + ln*4 + (nblk&3)  -> fragment nt of wave w, lane ln covers
// col w*64 + ln*4 + nt (thread's 4 output cols adjacent).
__global__ __launch_bounds__(256) void k_prepw2(
    const float* __restrict__ Wsrc, ushort* __restrict__ wpk)
{
    int gid = blockIdx.x * 256 + threadIdx.x;   // 8192 slots: (nblk*8+kk)*64+lane
    if (gid >= 8192) return;
    int lane = gid & 63;
    int kk   = (gid >> 6) & 7;
    int nblk = gid >> 9;
    int ln = lane & 15, g = lane >> 4;
    int n = ((nblk >> 2) << 6) + (ln << 2) + (nblk & 3);
    const float* src = Wsrc + (size_t)n * cE + kk * 32 + 4 * g;
    float4 x0 = *reinterpret_cast<const float4*>(src);
    float4 x1 = *reinterpret_cast<const float4*>(src + 16);
    float xs[8] = {x0.x, x0.y, x0.z, x0.w, x1.x, x1.y, x1.z, x1.w};
    union { ushort s[8]; uint4 q; } hi_, lo_;
#pragma unroll
    for (int j = 0; j < 8; j++) split_bf(xs[j], hi_.s[j], lo_.s[j]);
    *reinterpret_cast<uint4*>(wpk + (size_t)gid * 8)         = hi_.q;
    *reinterpret_cast<uint4*>(wpk + 65536 + (size_t)gid * 8) = lo_.q;
}

// ---------------------------------------------------------------- fused vproj GEMM v5 (M-block 128)
// C[160000][256] = A @ W^T + b, row-major C, float4 C-writes (col-permuted W pack).
// M-tile 128 rows/block: same 8 W loads per k-step feed 96 MFMAs (2x intensity vs W),
// W L2 traffic halved. Double-buffered global_load_lds staging; one barrier per
// k-step; rule-#21 XOR swizzle on both sides.
__global__ __launch_bounds__(256) void k_bgemm2(
    const float* __restrict__ A, const ushort* __restrict__ wpk2,
    const float* __restrict__ bias, float* __restrict__ vimg)
{
    __shared__ float lds[2][4096];   // two 128x32 fp32 tiles, linear (32 KB)
    const int t    = threadIdx.x;
    const int w    = t >> 6;
    const int lane = t & 63;
    const int g    = lane >> 4;
    const int ln   = lane & 15;
    const int bm   = blockIdx.x * 128;
    const ushort* wlo = wpk2 + 65536;

    f32x4 acc[8][4];
#pragma unroll
    for (int mt = 0; mt < 8; mt++)
#pragma unroll
        for (int nt = 0; nt < 4; nt++) acc[mt][nt] = {0.f, 0.f, 0.f, 0.f};

#define VSTAGE(buf, kkv) {                                                          \
    _Pragma("unroll")                                                               \
    for (int i_ = 0; i_ < 4; i_++) {                                                \
        int row_ = (w << 5) + (i_ << 3) + (lane >> 3);                              \
        int c_ = ((lane & 7) << 4) ^ ((row_ & 7) << 4);                             \
        gl_lds16(A + (size_t)(bm + row_) * cE + (kkv) * 32 + (c_ >> 2),             \
                 &lds[buf][(w << 10) + (i_ << 8)]);                                 \
    }                                                                               \
}

    VSTAGE(0, 0)
    __syncthreads();

#pragma unroll
    for (int kk = 0; kk < 8; kk++) {
        const int cur = kk & 1;
        if (kk < 7) VSTAGE(cur ^ 1, kk + 1)

        // W fragments (wave-contiguous, L2-resident)
        U8 wh[4], wl[4];
#pragma unroll
        for (int nt = 0; nt < 4; nt++) {
            size_t off = (((size_t)(w * 4 + nt) * 8 + kk) * 64 + lane) * 8;
            *reinterpret_cast<uint4*>(&wh[nt].u[0]) = *reinterpret_cast<const uint4*>(wpk2 + off);
            *reinterpret_cast<uint4*>(&wl[nt].u[0]) = *reinterpret_cast<const uint4*>(wlo + off);
        }

        // A fragments from swizzled LDS, split in-register, MFMA
        const char* lb = (const char*)(&lds[cur][0]);
#pragma unroll
        for (int mt = 0; mt < 8; mt++) {
            int row = mt * 16 + ln;
            int mk = (row & 7) << 4;
            float4 x0 = *reinterpret_cast<const float4*>(lb + row * 128 + ((g * 16) ^ mk));
            float4 x1 = *reinterpret_cast<const float4*>(lb + row * 128 + ((64 + g * 16) ^ mk));
            float xs[8] = {x0.x, x0.y, x0.z, x0.w, x1.x, x1.y, x1.z, x1.w};
            U8 aH, aL;
            union { ushort s[8]; uint u[4]; } hs, ls;
#pragma unroll
            for (int j = 0; j < 8; j++) split_bf(xs[j], hs.s[j], ls.s[j]);
#pragma unroll
            for (int i = 0; i < 4; i++) { aH.u[i] = hs.u[i]; aL.u[i] = ls.u[i]; }
#pragma unroll
            for (int nt = 0; nt < 4; nt++) {
                acc[mt][nt] = __builtin_amdgcn_mfma_f32_16x16x32_bf16(aL.v, wh[nt].v, acc[mt][nt], 0, 0, 0);
                acc[mt][nt] = __builtin_amdgcn_mfma_f32_16x16x32_bf16(aH.v, wl[nt].v, acc[mt][nt], 0, 0, 0);
                acc[mt][nt] = __builtin_amdgcn_mfma_f32_16x16x32_bf16(aH.v, wh[nt].v, acc[mt][nt], 0, 0, 0);
            }
        }
        __syncthreads();   // drains vmcnt(0): next tile's gload_lds complete; reads of lds[cur] done
    }
#undef VSTAGE

    // row-major C write, float4 per (mt,r): cols w*64 + ln*4 + {0,1,2,3}
    const int cb = w * 64 + ln * 4;
    float4 bv4 = *reinterpret_cast<const float4*>(&bias[cb]);
#pragma unroll
    for (int mt = 0; mt < 8; mt++) {
#pragma unroll
        for (int r = 0; r < 4; r++) {
            int gr = bm + mt * 16 + 4 * g + r;
            float4 o;
            o.x = acc[mt][0][r] + bv4.x;
            o.y = acc[mt][1][r] + bv4.y;
            o.z = acc[mt][2][r] + bv4.z;
            o.w = acc[mt][3][r] + bv4.w;
            *reinterpret_cast<float4*>(&vimg[(size_t)gr * cE + cb]) = o;
        }
    }
}

// ---------------------------------------------------------------- off/aw head GEMM: raw[8000][96] = xq @ Wcat^T
__global__ __launch_bounds__(256) void k_oagemm(
    const float* __restrict__ xq, const ushort* __restrict__ wpk,
    float* __restrict__ raw)
{
    const int w    = threadIdx.x >> 6;
    const int lane = threadIdx.x & 63;
    const int g    = lane >> 4;
    const int ln   = lane & 15;
    const int row0 = blockIdx.x * 64 + w * 16;
    const ushort* wlo = wpk + 24576;

    f32x4 acc[6];
#pragma unroll
    for (int nt = 0; nt < 6; nt++) acc[nt] = {0.f, 0.f, 0.f, 0.f};

    for (int kk = 0; kk < 8; kk++) {
        const float* ap = xq + (size_t)(row0 + ln) * cE + kk * 32 + 4 * g;
        float4 u0 = *reinterpret_cast<const float4*>(ap);
        float4 u1 = *reinterpret_cast<const float4*>(ap + 16);
        float xs[8] = {u0.x, u0.y, u0.z, u0.w, u1.x, u1.y, u1.z, u1.w};
        U8 aH, aL;
        union { ushort s[8]; uint u[4]; } hs, ls;
#pragma unroll
        for (int j = 0; j < 8; j++) split_bf(xs[j], hs.s[j], ls.s[j]);
#pragma unroll
        for (int i = 0; i < 4; i++) { aH.u[i] = hs.u[i]; aL.u[i] = ls.u[i]; }
#pragma unroll
        for (int nt = 0; nt < 6; nt++) {
            int n = nt * 16 + ln;
            size_t off = ((size_t)(n * 8 + kk) * 4 + g) * 8;
            U8 wh, wl;
            *reinterpret_cast<uint4*>(&wh.u[0]) = *reinterpret_cast<const uint4*>(wpk + off);
            *reinterpret_cast<uint4*>(&wl.u[0]) = *reinterpret_cast<const uint4*>(wlo + off);
            acc[nt] = __builtin_amdgcn_mfma_f32_16x16x32_bf16(aL.v, wh.v, acc[nt], 0, 0, 0);
            acc[nt] = __builtin_amdgcn_mfma_f32_16x16x32_bf16(aH.v, wl.v, acc[nt], 0, 0, 0);
            acc[nt] = __builtin_amdgcn_mfma_f32_16x16x32_bf16(aH.v, wh.v, acc[nt], 0, 0, 0);
        }
    }

#pragma unroll
    for (int nt = 0; nt < 6; nt++) {
        int n = nt * 16 + ln;
#pragma unroll
        for (int r = 0; r < 4; r++) {
            int row = row0 + 4 * g + r;
            raw[(size_t)row * 96 + n] = acc[nt][r];
        }
    }
}

// ---------------------------------------------------------------- loc/aw postprocess
__global__ __launch_bounds__(256) void k_locaw(
    const float* __restrict__ raw, const float* __restrict__ offb,
    const float* __restrict__ awbias, const float* __restrict__ refp,
    float* __restrict__ locO, float* __restrict__ awO)
{
    int gid = blockIdx.x * 256 + threadIdx.x;   // 8000*96
    if (gid >= NTOK * 96) return;
    int i = gid % 96;
    int tok = gid / 96;
    int q = tok >> 3, b = tok & 7;
    int bq = b * cNQ + q;
    const float* rr = raw + (size_t)tok * 96;
    if (i < 64) {
        int c = i & 1;
        float offv = rr[i] + offb[i];
        float refv = refp[((size_t)b * cNQ + q) * 2 + c];
        float nrm = (c == 0) ? 200.f : 100.f;
        locO[(size_t)bq * 64 + i] = refv + offv / nrm;
    } else {
        int j = i - 64;            // j = h*4+p
        int gbase = j & ~3;
        float x0 = rr[64 + gbase + 0] + awbias[gbase + 0];
        float x1 = rr[64 + gbase + 1] + awbias[gbase + 1];
        float x2 = rr[64 + gbase + 2] + awbias[gbase + 2];
        float x3 = rr[64 + gbase + 3] + awbias[gbase + 3];
        float xm = rr[64 + j] + awbias[j];
        float mx = fmaxf(fmaxf(x0, x1), fmaxf(x2, x3));
        float e = __expf(xm - mx);
        float ssum = __expf(x0 - mx) + __expf(x1 - mx) + __expf(x2 - mx) + __expf(x3 - mx);
        awO[(size_t)bq * 32 + j] = e / ssum;
    }
}

// ---------------------------------------------------------------- unified split-precision MFMA GEMM (small GEMMs)
constexpr int MM_QKV   = 1;
constexpr int MM_PLAIN = 2;
constexpr int MM_RELU  = 3;
constexpr int MM_OPROJ = 4;

template <int MODE, int TKK, int NFULL>
__global__ __launch_bounds__(256) void k_mgemm(
    const float* __restrict__ A, const float* __restrict__ A2,
    const ushort* __restrict__ wpk, int losz,
    const float* __restrict__ bias,
    void* __restrict__ C0, void* __restrict__ C1, void* __restrict__ C2)
{
    const int w    = threadIdx.x >> 6;
    const int lane = threadIdx.x & 63;
    const int g    = lane >> 4;
    const int ln   = lane & 15;
    const int bm   = blockIdx.x * 32;
    const int slab = blockIdx.y;
    const int nb   = slab * 256 + w * 64;
    const ushort* wlo = wpk + losz;
    const int K = TKK * 32;

    f32x4 acc[2][4];
#pragma unroll
    for (int mt = 0; mt < 2; mt++)
#pragma unroll
        for (int nt = 0; nt < 4; nt++) acc[mt][nt] = {0.f, 0.f, 0.f, 0.f};

    U8 wh[2][4], wl[2][4];
    float ax[2][2][8];

#define MG_LOADW(kk, buf) {                                                        \
    _Pragma("unroll")                                                              \
    for (int nt = 0; nt < 4; nt++) {                                               \
        int n = nb + nt * 16 + ln;                                                 \
        size_t off = ((size_t)(n * TKK + (kk)) * 4 + g) * 8;                       \
        *reinterpret_cast<uint4*>(&wh[buf][nt].u[0]) = *reinterpret_cast<const uint4*>(wpk + off); \
        *reinterpret_cast<uint4*>(&wl[buf][nt].u[0]) = *reinterpret_cast<const uint4*>(wlo + off); \
    } }

#define MG_LOADA(kk, buf) {                                                        \
    _Pragma("unroll")                                                              \
    for (int mt = 0; mt < 2; mt++) {                                               \
        const float* ap = A + (size_t)(bm + mt * 16 + ln) * K + (kk) * 32 + 4 * g; \
        float4 u0 = *reinterpret_cast<const float4*>(ap);                          \
        float4 u1 = *reinterpret_cast<const float4*>(ap + 16);                     \
        if (MODE == MM_QKV && slab < 2) {                                          \
            const float* bp = A2 + (size_t)(bm + mt * 16 + ln) * K + (kk) * 32 + 4 * g; \
            float4 v0 = *reinterpret_cast<const float4*>(bp);                      \
            float4 v1 = *reinterpret_cast<const float4*>(bp + 16);                 \
            u0.x += v0.x; u0.y += v0.y; u0.z += v0.z; u0.w += v0.w;                \
            u1.x += v1.x; u1.y += v1.y; u1.z += v1.z; u1.w += v1.w;                \
        }                                                                          \
        ax[buf][mt][0] = u0.x; ax[buf][mt][1] = u0.y;                              \
        ax[buf][mt][2] = u0.z; ax[buf][mt][3] = u0.w;                              \
        ax[buf][mt][4] = u1.x; ax[buf][mt][5] = u1.y;                              \
        ax[buf][mt][6] = u1.z; ax[buf][mt][7] = u1.w;                              \
    } }

#define MG_STEP(buf) {                                                             \
    _Pragma("unroll")                                                              \
    for (int mt = 0; mt < 2; mt++) {                                               \
        U8 aH, aL;                                                                 \
        union { ushort s[8]; uint u[4]; } hs, ls;                                  \
        _Pragma("unroll")                                                          \
        for (int j = 0; j < 8; j++) split_bf(ax[buf][mt][j], hs.s[j], ls.s[j]);    \
        _Pragma("unroll")                                                          \
        for (int i = 0; i < 4; i++) { aH.u[i] = hs.u[i]; aL.u[i] = ls.u[i]; }      \
        _Pragma("unroll")                                                          \
        for (int nt = 0; nt < 4; nt++) {                                           \
            acc[mt][nt] = __builtin_amdgcn_mfma_f32_16x16x32_bf16(aL.v, wh[buf][nt].v, acc[mt][nt], 0, 0, 0); \
            acc[mt][nt] = __builtin_amdgcn_mfma_f32_16x16x32_bf16(aH.v, wl[buf][nt].v, acc[mt][nt], 0, 0, 0); \
            acc[mt][nt] = __builtin_amdgcn_mfma_f32_16x16x32_bf16(aH.v, wh[buf][nt].v, acc[mt][nt], 0, 0, 0); \
        }                                                                          \
    } }

    MG_LOADW(0, 0)
    MG_LOADA(0, 0)
#pragma unroll
    for (int kk = 0; kk < TKK; kk++) {
        if (kk + 1 < TKK) {
            MG_LOADW(kk + 1, (kk + 1) & 1)
            MG_LOADA(kk + 1, (kk + 1) & 1)
        }
        MG_STEP(kk & 1)
    }
#undef MG_LOADW
#undef MG_LOADA
#undef MG_STEP

#pragma unroll
    for (int nt = 0; nt < 4; nt++) {
        int n = nb + nt * 16 + ln;
        float bv = bias[n];
#pragma unroll
        for (int mt = 0; mt < 2; mt++) {
#pragma unroll
            for (int r = 0; r < 4; r++) {
                int gr = bm + mt * 16 + 4 * g + r;
                float val = acc[mt][nt][r] + bv;
                if (MODE == MM_QKV) {
                    int tok = gr >> 3, b = gr & 7;
                    int nloc = n & 255, h = nloc >> 5, d = nloc & 31;
                    if (slab == 0) val *= 0.17677669529663687f; // 1/sqrt(32)
                    ushort hs, ls;
                    split_bf(val, hs, ls);
                    if (slab < 2) {
                        // fragment-contiguous: slot(d) = ((d>>2)&3)*8 + (d&3) + 4*(d>>4)
                        int slot = ((d >> 2) & 3) * 8 + (d & 3) + 4 * (d >> 4);
                        ushort* base = (slab == 0) ? (ushort*)C0 : (ushort*)C1;
                        size_t off = ((size_t)(b * cHH + h) * 1024 + tok) * 32 + slot;
                        base[off]         = hs;
                        base[QKSZ2 + off] = ls;
                    } else {
                        // V: [bh][d][tokblk][slot], slot(o) over tok offset within 32-block
                        int o = tok & 31, kbi = tok >> 5;
                        int slot = ((o >> 2) & 3) * 8 + (o & 3) + 4 * (o >> 4);
                        ushort* vb = (ushort*)C2;
                        size_t off = ((size_t)(b * cHH + h) * 32 + d) * 1024 + kbi * 32 + slot;
                        vb[off]         = hs;
                        vb[QKSZ2 + off] = ls;
                    }
                } else if (MODE == MM_OPROJ) {
                    int b = gr / cNQ, q = gr - b * cNQ;
                    ((float*)C0)[((size_t)q * cBS + b) * cE + n] = val;
                } else {
                    if (MODE == MM_RELU) val = fmaxf(val, 0.f);
                    ((float*)C0)[(size_t)gr * NFULL + n] = val;
                }
            }
        }
    }
}

// ---------------------------------------------------------------- MFMA flash attention (v8: 2x Q-blocking, XCD swizzle, K-split)
__global__ __launch_bounds__(256) void k_attn3(
    const ushort* __restrict__ qhi, const ushort* __restrict__ qlo,
    const ushort* __restrict__ khi, const ushort* __restrict__ klo,
    const ushort* __restrict__ vhi, const ushort* __restrict__ vlo,
    float* __restrict__ po, float* __restrict__ plsum)
{
    const int bid   = blockIdx.x;           // 1024 blocks
    const int xcd   = bid & 7;
    const int inner = bid >> 3;             // 0..127
    const int bh    = ((inner & 7) << 3) + xcd;   // bh % 8 == bid % 8
    const int rest  = inner >> 3;           // 0..15
    const int qbix  = rest & 7;             // q-block of 128 rows
    const int z     = rest >> 3;            // 0..1

    const int w    = threadIdx.x >> 6;
    const int lane = threadIdx.x & 63;
    const int g    = lane >> 4;
    const int ql   = lane & 15;
    const int qA   = qbix * 128 + w * 32;   // wave: rows [qA, qA+16) and [qA+16, qA+32)

    const size_t qoffA = ((size_t)bh * 1024 + qA + ql) * 32 + g * 8;
    U8 bQAh, bQAl, bQBh, bQBl;
    *reinterpret_cast<uint4*>(&bQAh.u[0]) = *reinterpret_cast<const uint4*>(qhi + qoffA);
    *reinterpret_cast<uint4*>(&bQAl.u[0]) = *reinterpret_cast<const uint4*>(qlo + qoffA);
    *reinterpret_cast<uint4*>(&bQBh.u[0]) = *reinterpret_cast<const uint4*>(qhi + qoffA + 16 * 32);
    *reinterpret_cast<uint4*>(&bQBl.u[0]) = *reinterpret_cast<const uint4*>(qlo + qoffA + 16 * 32);
    const size_t koff = ((size_t)bh * 1024 + ql) * 32 + g * 8;
    const size_t voff = ((size_t)bh * 32 + ql) * 1024 + g * 8;

    f32x4 oA0 = {0.f,0.f,0.f,0.f}, oA1 = {0.f,0.f,0.f,0.f};
    f32x4 oB0 = {0.f,0.f,0.f,0.f}, oB1 = {0.f,0.f,0.f,0.f};
    float lpartA = 0.f, lpartB = 0.f;
    const f32x4 zz = {0.f, 0.f, 0.f, 0.f};

    const int kt0 = z * 16;
#pragma unroll
    for (int kti = 0; kti < 16; kti++) {
        const int kt = kt0 + kti;
        U8 k0h, k1h, k0l, k1l, v0h, v1h, v0l, v1l;
        {
            size_t kb32 = (size_t)kt * 32 * 32;
            *reinterpret_cast<uint4*>(&k0h.u[0]) = *reinterpret_cast<const uint4*>(khi + koff + kb32);
            *reinterpret_cast<uint4*>(&k1h.u[0]) = *reinterpret_cast<const uint4*>(khi + koff + kb32 + 512);
            *reinterpret_cast<uint4*>(&k0l.u[0]) = *reinterpret_cast<const uint4*>(klo + koff + kb32);
            *reinterpret_cast<uint4*>(&k1l.u[0]) = *reinterpret_cast<const uint4*>(klo + koff + kb32 + 512);
            size_t vb32 = voff + (size_t)kt * 32;
            *reinterpret_cast<uint4*>(&v0h.u[0]) = *reinterpret_cast<const uint4*>(vhi + vb32);
            *reinterpret_cast<uint4*>(&v1h.u[0]) = *reinterpret_cast<const uint4*>(vhi + vb32 + 16 * 1024);
            *reinterpret_cast<uint4*>(&v0l.u[0]) = *reinterpret_cast<const uint4*>(vlo + vb32);
            *reinterpret_cast<uint4*>(&v1l.u[0]) = *reinterpret_cast<const uint4*>(vlo + vb32 + 16 * 1024);
        }

        const bool tail = (kti == 15) && (z == 1);

        f32x4 sA0 = __builtin_amdgcn_mfma_f32_16x16x32_bf16(k0l.v, bQAh.v, zz, 0, 0, 0);
        sA0 = __builtin_amdgcn_mfma_f32_16x16x32_bf16(k0h.v, bQAl.v, sA0, 0, 0, 0);
        sA0 = __builtin_amdgcn_mfma_f32_16x16x32_bf16(k0h.v, bQAh.v, sA0, 0, 0, 0);
        f32x4 sB0 = __builtin_amdgcn_mfma_f32_16x16x32_bf16(k0l.v, bQBh.v, zz, 0, 0, 0);
        sB0 = __builtin_amdgcn_mfma_f32_16x16x32_bf16(k0h.v, bQBl.v, sB0, 0, 0, 0);
        sB0 = __builtin_amdgcn_mfma_f32_16x16x32_bf16(k0h.v, bQBh.v, sB0, 0, 0, 0);
        f32x4 sA1, sB1;
        if (tail) {
            int tb = 31 * 32 + 4 * g;
#pragma unroll
            for (int r = 0; r < 4; r++) {
                if (tb + r >= cNQ) { sA0[r] = -INFINITY; sB0[r] = -INFINITY; }
            }
            sA1[0] = sA1[1] = sA1[2] = sA1[3] = -INFINITY;
            sB1[0] = sB1[1] = sB1[2] = sB1[3] = -INFINITY;
        } else {
            sA1 = __builtin_amdgcn_mfma_f32_16x16x32_bf16(k1l.v, bQAh.v, zz, 0, 0, 0);
            sA1 = __builtin_amdgcn_mfma_f32_16x16x32_bf16(k1h.v, bQAl.v, sA1, 0, 0, 0);
            sA1 = __builtin_amdgcn_mfma_f32_16x16x32_bf16(k1h.v, bQAh.v, sA1, 0, 0, 0);
            sB1 = __builtin_amdgcn_mfma_f32_16x16x32_bf16(k1l.v, bQBh.v, zz, 0, 0, 0);
            sB1 = __builtin_amdgcn_mfma_f32_16x16x32_bf16(k1h.v, bQBl.v, sB1, 0, 0, 0);
            sB1 = __builtin_amdgcn_mfma_f32_16x16x32_bf16(k1h.v, bQBh.v, sB1, 0, 0, 0);
        }

        float pA00 = __expf(sA0[0]), pA01 = __expf(sA0[1]);
        float pA02 = __expf(sA0[2]), pA03 = __expf(sA0[3]);
        float pA10 = __expf(sA1[0]), pA11 = __expf(sA1[1]);
        float pA12 = __expf(sA1[2]), pA13 = __expf(sA1[3]);
        lpartA += ((pA00 + pA01) + (pA02 + pA03)) + ((pA10 + pA11) + (pA12 + pA13));
        float pB00 = __expf(sB0[0]), pB01 = __expf(sB0[1]);
        float pB02 = __expf(sB0[2]), pB03 = __expf(sB0[3]);
        float pB10 = __expf(sB1[0]), pB11 = __expf(sB1[1]);
        float pB12 = __expf(sB1[2]), pB13 = __expf(sB1[3]);
        lpartB += ((pB00 + pB01) + (pB02 + pB03)) + ((pB10 + pB11) + (pB12 + pB13));

        U8 fpAh, fpAl, fpBh, fpBl;
        pk_split2(pA00, pA01, fpAh.u[0], fpAl.u[0]);
        pk_split2(pA02, pA03, fpAh.u[1], fpAl.u[1]);
        pk_split2(pA10, pA11, fpAh.u[2], fpAl.u[2]);
        pk_split2(pA12, pA13, fpAh.u[3], fpAl.u[3]);
        pk_split2(pB00, pB01, fpBh.u[0], fpBl.u[0]);
        pk_split2(pB02, pB03, fpBh.u[1], fpBl.u[1]);
        pk_split2(pB10, pB11, fpBh.u[2], fpBl.u[2]);
        pk_split2(pB12, pB13, fpBh.u[3], fpBl.u[3]);

        oA0 = __builtin_amdgcn_mfma_f32_16x16x32_bf16(v0l.v, fpAh.v, oA0, 0, 0, 0);
        oA0 = __builtin_amdgcn_mfma_f32_16x16x32_bf16(v0h.v, fpAl.v, oA0, 0, 0, 0);
        oA0 = __builtin_amdgcn_mfma_f32_16x16x32_bf16(v0h.v, fpAh.v, oA0, 0, 0, 0);
        oA1 = __builtin_amdgcn_mfma_f32_16x16x32_bf16(v1l.v, fpAh.v, oA1, 0, 0, 0);
        oA1 = __builtin_amdgcn_mfma_f32_16x16x32_bf16(v1h.v, fpAl.v, oA1, 0, 0, 0);
        oA1 = __builtin_amdgcn_mfma_f32_16x16x32_bf16(v1h.v, fpAh.v, oA1, 0, 0, 0);
        oB0 = __builtin_amdgcn_mfma_f32_16x16x32_bf16(v0l.v, fpBh.v, oB0, 0, 0, 0);
        oB0 = __builtin_amdgcn_mfma_f32_16x16x32_bf16(v0h.v, fpBl.v, oB0, 0, 0, 0);
        oB0 = __builtin_amdgcn_mfma_f32_16x16x32_bf16(v0h.v, fpBh.v, oB0, 0, 0, 0);
        oB1 = __builtin_amdgcn_mfma_f32_16x16x32_bf16(v1l.v, fpBh.v, oB1, 0, 0, 0);
        oB1 = __builtin_amdgcn_mfma_f32_16x16x32_bf16(v1h.v, fpBl.v, oB1, 0, 0, 0);
        oB1 = __builtin_amdgcn_mfma_f32_16x16x32_bf16(v1h.v, fpBh.v, oB1, 0, 0, 0);
    }

    // per-lane partial denominators -> per-q via 2 xor-shfls (same q across g groups)
    float lsumA = lpartA;
    lsumA += __shfl_xor(lsumA, 16, 64);
    lsumA += __shfl_xor(lsumA, 32, 64);
    float lsumB = lpartB;
    lsumB += __shfl_xor(lsumB, 16, 64);
    lsumB += __shfl_xor(lsumB, 32, 64);

    {
        const int q = qA + ql;
        if (q < cNQ) {
            size_t base = ((size_t)(z * 64 + bh) * 1000 + q) * 32;
            float4 v0, v1;
            v0.x = oA0[0]; v0.y = oA0[1]; v0.z = oA0[2]; v0.w = oA0[3];
            v1.x = oA1[0]; v1.y = oA1[1]; v1.z = oA1[2]; v1.w = oA1[3];
            *reinterpret_cast<float4*>(po + base + 4 * g)      = v0;
            *reinterpret_cast<float4*>(po + base + 16 + 4 * g) = v1;
            if (g == 0) plsum[(size_t)(z * 64 + bh) * 1000 + q] = lsumA;
        }
    }
    {
        const int q = qA + 16 + ql;
        if (q < cNQ) {
            size_t base = ((size_t)(z * 64 + bh) * 1000 + q) * 32;
            float4 v0, v1;
            v0.x = oB0[0]; v0.y = oB0[1]; v0.z = oB0[2]; v0.w = oB0[3];
            v1.x = oB1[0]; v1.y = oB1[1]; v1.z = oB1[2]; v1.w = oB1[3];
            *reinterpret_cast<float4*>(po + base + 4 * g)      = v0;
            *reinterpret_cast<float4*>(po + base + 16 + 4 * g) = v1;
            if (g == 0) plsum[(size_t)(z * 64 + bh) * 1000 + q] = lsumB;
        }
    }
}

// ---------------------------------------------------------------- attention partial reduce
__global__ __launch_bounds__(256) void k_ared(
    const float* __restrict__ po, const float* __restrict__ plsum,
    float* __restrict__ outp)
{
    int gid = blockIdx.x * 256 + threadIdx.x;   // 64*1000*32 = 2,048,000
    if (gid >= 64 * 1000 * 32) return;
    int d   = gid & 31;
    int rem = gid >> 5;         // bh*1000 + q
    int q   = rem % 1000;
    int bh  = rem / 1000;
    float o = po[gid] + po[(size_t)64 * 1000 * 32 + gid];
    float l = plsum[rem] + plsum[64000 + rem];
    int b = bh >> 3, h = bh & 7;
    outp[((size_t)q * cBS + b) * cE + h * 32 + d] = o / l;
}

// ---------------------------------------------------------------- layernorm
__global__ __launch_bounds__(256) void k_ln(
    const float* __restrict__ a, const float* __restrict__ b,
    const float* __restrict__ w, const float* __restrict__ bias,
    const float* __restrict__ addc,
    float* __restrict__ outp, float* __restrict__ out2)
{
    int rrow = blockIdx.x, t = threadIdx.x;
    size_t base = (size_t)rrow * cE;
    float v = a[base + t] + b[base + t];
    float s = v;
#pragma unroll
    for (int off = 32; off > 0; off >>= 1) s += __shfl_down(s, off, 64);
    __shared__ float red1[4], red2[4];
    int wid = t >> 6, lane = t & 63;
    if (lane == 0) red1[wid] = s;
    __syncthreads();
    float mu = (red1[0] + red1[1] + red1[2] + red1[3]) * (1.f / cE);
    float e = v - mu;
    float s2 = e * e;
#pragma unroll
    for (int off = 32; off > 0; off >>= 1) s2 += __shfl_down(s2, off, 64);
    if (lane == 0) red2[wid] = s2;
    __syncthreads();
    float var = (red2[0] + red2[1] + red2[2] + red2[3]) * (1.f / cE);
    float y = e * (1.f / sqrtf(var + 1e-5f)) * w[t] + bias[t];
    outp[base + t] = y;
    if (out2 != nullptr) out2[base + t] = y + addc[base + t];
}

// ---------------------------------------------------------------- MSDA sampling (vimg row-major [tok][E], tok = nv*BS + b)
__device__ __forceinline__ float samp_one(const float* __restrict__ img, int x, int y)
{
    bool ok = (x >= 0) & (x < cW) & (y >= 0) & (y < cH);
    int xc = min(max(x, 0), cW - 1);
    int yc = min(max(y, 0), cH - 1);
    float v = img[(size_t)(yc * cW + xc) * (cBS * cE)];
    return ok ? v : 0.f;
}

__global__ __launch_bounds__(256) void k_msda(
    const float* __restrict__ vimg, const float* __restrict__ loc,
    const float* __restrict__ aw, float* __restrict__ msp)
{
    int gid = blockIdx.x * 256 + threadIdx.x;
    int d  = gid & 31;
    int h  = (gid >> 5) & 7;
    int bq = gid >> 8;
    int b  = bq / cNQ;
    const float* lp = loc + ((size_t)bq * cHH + h) * (cP * 2);
    const float* ap = aw + ((size_t)bq * cHH + h) * cP;
    const float* img = vimg + (size_t)b * cE + h * cDH + d;
    float acc = 0.f;
#pragma unroll
    for (int p = 0; p < cP; p++) {
        float g0 = 2.f * lp[p * 2 + 0] - 1.f;
        float g1 = 2.f * lp[p * 2 + 1] - 1.f;
        float xf = (g0 + 1.f) * 0.5f * (float)cW - 0.5f;
        float yf = (g1 + 1.f) * 0.5f * (float)cH - 0.5f;
        float x0f = floorf(xf), y0f = floorf(yf);
        float wx = xf - x0f, wy = yf - y0f;
        int x0 = (int)x0f, y0 = (int)y0f;
        float v00 = samp_one(img, x0,     y0);
        float v01 = samp_one(img, x0 + 1, y0);
        float v10 = samp_one(img, x0,     y0 + 1);
        float v11 = samp_one(img, x0 + 1, y0 + 1);
        float bil = v00 * (1.f - wx) * (1.f - wy) + v01 * wx * (1.f - wy)
                  + v10 * (1.f - wx) * wy        + v11 * wx * wy;
        acc = fmaf(bil, ap[p], acc);
    }
    msp[gid] = acc;
}

// ---------------------------------------------------------------- launch
extern "C" void kernel_launch(void* const* d_in, const int* in_sizes, int n_in,
                              void* d_out, int out_size, void* d_ws, size_t ws_size,
                              hipStream_t stream)
{
    const float* query = (const float*)d_in[0];
    const float* qpos  = (const float*)d_in[1];
    const float* value = (const float*)d_in[2];
    const float* refp  = (const float*)d_in[3];
    const float* inw   = (const float*)d_in[4];
    const float* inb   = (const float*)d_in[5];
    const float* outw  = (const float*)d_in[6];
    const float* outb  = (const float*)d_in[7];
    const float* ln1w  = (const float*)d_in[8];
    const float* ln1b  = (const float*)d_in[9];
    const float* ln2w  = (const float*)d_in[10];
    const float* ln2b  = (const float*)d_in[11];
    const float* ln3w  = (const float*)d_in[12];
    const float* ln3b  = (const float*)d_in[13];
    const float* offw  = (const float*)d_in[14];
    const float* offb  = (const float*)d_in[15];
    const float* aww   = (const float*)d_in[16];
    const float* awbias= (const float*)d_in[17];
    const float* vpw   = (const float*)d_in[18];
    const float* vpb   = (const float*)d_in[19];
    const float* opw   = (const float*)d_in[20];
    const float* opb   = (const float*)d_in[21];
    const float* f1w   = (const float*)d_in[22];
    const float* f1b   = (const float*)d_in[23];
    const float* f2w   = (const float*)d_in[24];
    const float* f2b   = (const float*)d_in[25];
    float* out = (float*)d_out;

    float* ws = (float*)d_ws;
    const size_t S = (size_t)NTOK * cE;              // 2,048,000 floats
    const size_t BPADF = 6 * QKSZ2 / 2;              // 6,291,456 floats
    const size_t WPKF = 655360 + 24576;              // packed weights
    const size_t PLS  = 128000;                      // plsum[2][64][1000]
    const size_t need = 2 * S + BPADF + 512000 + 256000 + WPKF + PLS + (size_t)cBS * cHH * cNV * cDH;
    if (ws_size < need * sizeof(float)) return;

    float* P0   = ws;
    float* P1   = ws + S;
    float* Bpad = ws + 2 * S;
    float* locb = Bpad + BPADF;
    float* awb2 = locb + 512000;
    float* wpkf = awb2 + 256000;
    float* plsb = wpkf + WPKF;
    float* vimg = plsb + PLS;

    ushort* qhi = (ushort*)Bpad;
    ushort* qlo = qhi + QKSZ2;
    ushort* khi = qhi + 2 * QKSZ2;
    ushort* klo = qhi + 3 * QKSZ2;
    ushort* vhi = qhi + 4 * QKSZ2;
    ushort* vlo = qhi + 5 * QKSZ2;

    ushort* wpk_vp = (ushort*)wpkf;            // 131072 (wave-contiguous: hi 65536 + lo)
    ushort* wpk_in = wpk_vp + 131072;          // 393216
    ushort* wpk_ou = wpk_in + 393216;          // 131072
    ushort* wpk_op = wpk_ou + 131072;          // 131072
    ushort* wpk_f1 = wpk_op + 131072;          // 262144
    ushort* wpk_f2 = wpk_f1 + 262144;          // 262144
    ushort* wpk_oa = wpk_f2 + 262144;          // 49152 (96 rows: hi 24576 + lo)

    // pack weights
    k_prepw2<<<dim3(32), dim3(256), 0, stream>>>(vpw, wpk_vp);
    k_prepw<<<dim3(96), dim3(256), 0, stream>>>(inw,  wpk_in, 8,  24576, 196608);
    k_prepw<<<dim3(32), dim3(256), 0, stream>>>(outw, wpk_ou, 8,  8192,  65536);
    k_prepw<<<dim3(32), dim3(256), 0, stream>>>(opw,  wpk_op, 8,  8192,  65536);
    k_prepw<<<dim3(64), dim3(256), 0, stream>>>(f1w,  wpk_f1, 8,  16384, 131072);
    k_prepw<<<dim3(64), dim3(256), 0, stream>>>(f2w,  wpk_f2, 16, 16384, 131072);
    k_prepw<<<dim3(8),  dim3(256), 0, stream>>>(offw, wpk_oa, 8,  2048,  24576);
    k_prepw<<<dim3(4),  dim3(256), 0, stream>>>(aww,  wpk_oa + 16384, 8, 1024, 24576);

    // value projection: fused gload_lds-pipelined split + MFMA GEMM, M-tile 128
    k_bgemm2<<<dim3(1250), dim3(256), 0, stream>>>(value, wpk_vp, vpb, vimg);

    // zero V pad region (unwritten slots must be finite; 0*p=0)
    k_zerou4<<<dim3(2048), dim3(256), 0, stream>>>(
        reinterpret_cast<uint4*>(vhi), (int)(2 * QKSZ2 * 2 / 16));

    // QKV projection (q,k from query+qpos fused; v from query) -> fragment-contiguous bf16 hi/lo
    k_mgemm<MM_QKV, 8, 768><<<dim3(250, 3), dim3(256), 0, stream>>>(
        query, qpos, wpk_in, 196608, inb, qhi, khi, vhi);

    // split-precision MFMA flash attention, 2x Q-blocked, 2-way K-split, XCD-swizzled
    k_attn3<<<dim3(1024), dim3(256), 0, stream>>>(
        qhi, qlo, khi, klo, vhi, vlo, P0, plsb);

    // combine partials -> attn_pre (qhi/qlo region of Bpad, dead after attn3)
    float* attn_pre = Bpad;
    k_ared<<<dim3(8000), dim3(256), 0, stream>>>(P0, plsb, attn_pre);

    // out-proj
    float* mha_y = P1;
    k_mgemm<MM_PLAIN, 8, 256><<<dim3(250, 1), dim3(256), 0, stream>>>(
        attn_pre, nullptr, wpk_ou, 65536, outb, mha_y, nullptr, nullptr);

    // LN1: x = LN(query + mha_y), xq = x + query_pos
    float* x  = Bpad;
    float* xq = Bpad + S;
    k_ln<<<dim3(NTOK), dim3(256), 0, stream>>>(query, mha_y, ln1w, ln1b, qpos, x, xq);

    // off/aw head: GEMM (raw = xq @ Wcat^T) + loc/softmax postprocess
    float* rawb = P0;
    k_oagemm<<<dim3(125), dim3(256), 0, stream>>>(xq, wpk_oa, rawb);
    k_locaw<<<dim3((NTOK * 96 + 255) / 256), dim3(256), 0, stream>>>(
        rawb, offb, awbias, refp, locb, awb2);

    // MSDA bilinear sample
    float* ms_pre = P1;
    k_msda<<<dim3(NTOK * cE / 256), dim3(256), 0, stream>>>(vimg, locb, awb2, ms_pre);

    // oproj (rows (b,q) -> write (q,b))
    float* ms_y = P0;
    k_mgemm<MM_OPROJ, 8, 256><<<dim3(250, 1), dim3(256), 0, stream>>>(
        ms_pre, nullptr, wpk_op, 65536, opb, ms_y, nullptr, nullptr);

    // LN2: x2 = LN(x + ms_y)
    float* x2 = Bpad + 2 * S;
    k_ln<<<dim3(NTOK), dim3(256), 0, stream>>>(x, ms_y, ln2w, ln2b, nullptr, x2, nullptr);

    // FFN (hbuf reuses Bpad[0..2S) — x/xq dead)
    float* hbuf = Bpad;
    k_mgemm<MM_RELU, 8, 512><<<dim3(250, 2), dim3(256), 0, stream>>>(
        x2, nullptr, wpk_f1, 131072, f1b, hbuf, nullptr, nullptr);
    float* y3 = P0;
    k_mgemm<MM_PLAIN, 16, 256><<<dim3(250, 1), dim3(256), 0, stream>>>(
        hbuf, nullptr, wpk_f2, 131072, f2b, y3, nullptr, nullptr);

    // LN3 -> out
    k_ln<<<dim3(NTOK), dim3(256), 0, stream>>>(x2, y3, ln3w, ln3b, nullptr, out, nullptr);
}

// Round 22
// 409.953 us; speedup vs baseline: 1.0884x; 1.0884x over previous
//
#include <hip/hip_runtime.h>
#include <hip/hip_bf16.h>
#include <cmath>

constexpr int cBS = 8;
constexpr int cNQ = 1000;
constexpr int cNV = 20000;
constexpr int cE  = 256;
constexpr int cHH = 8;
constexpr int cDH = 32;
constexpr int cP  = 4;
constexpr int cFFN = 512;
constexpr int cH = 100;
constexpr int cW = 200;
constexpr int NTOK = cNQ * cBS;   // 8000
constexpr size_t QKSZ2 = (size_t)64 * 1024 * cDH;  // 2,097,152 ushorts per padded bf16 buffer

typedef float f32x4 __attribute__((ext_vector_type(4)));
typedef short bf16x8 __attribute__((ext_vector_type(8)));
union U8 { uint u[4]; bf16x8 v; };

__device__ __forceinline__ void split_bf(float x, ushort& h, ushort& l) {
    __hip_bfloat16 hb = __float2bfloat16(x);
    float hf = __bfloat162float(hb);
    __hip_bfloat16 lb = __float2bfloat16(x - hf);
    h = *reinterpret_cast<ushort*>(&hb);
    l = *reinterpret_cast<ushort*>(&lb);
}
__device__ __forceinline__ void pk_split2(float a, float b, uint& h, uint& l) {
    __hip_bfloat16 ah = __float2bfloat16(a), bh = __float2bfloat16(b);
    float arf = a - __bfloat162float(ah), brf = b - __bfloat162float(bh);
    __hip_bfloat16 al = __float2bfloat16(arf), bl = __float2bfloat16(brf);
    h = ((uint)*reinterpret_cast<ushort*>(&bh) << 16) | *reinterpret_cast<ushort*>(&ah);
    l = ((uint)*reinterpret_cast<ushort*>(&bl) << 16) | *reinterpret_cast<ushort*>(&al);
}

__device__ __forceinline__ void gl_lds16(const float* g, float* l) {
    __builtin_amdgcn_global_load_lds(
        (const __attribute__((address_space(1))) unsigned int*)g,
        (__attribute__((address_space(3))) unsigned int*)l,
        16, 0, 0);
}

__global__ __launch_bounds__(256) void k_zerou4(uint4* __restrict__ p, int n)
{
    int i = blockIdx.x * 256 + threadIdx.x;
    if (i < n) p[i] = uint4{0u, 0u, 0u, 0u};
}

// ---------------------------------------------------------------- weight prep (per-lane fragment layout)
__global__ __launch_bounds__(256) void k_prepw(
    const float* __restrict__ Wsrc, ushort* __restrict__ wpk,
    int nkk /* K/32 */, int total /* N*4*nkk */, int losz /* N*K elems */)
{
    int gid = blockIdx.x * 256 + threadIdx.x;
    if (gid >= total) return;
    int g  = gid & 3;
    int kk = (gid >> 2) % nkk;
    int n  = gid / (4 * nkk);
    const float* src = Wsrc + (size_t)n * (nkk * 32) + kk * 32 + 4 * g;
    float4 x0 = *reinterpret_cast<const float4*>(src);
    float4 x1 = *reinterpret_cast<const float4*>(src + 16);
    float xs[8] = {x0.x, x0.y, x0.z, x0.w, x1.x, x1.y, x1.z, x1.w};
    union { ushort s[8]; uint4 q; } hi_, lo_;
#pragma unroll
    for (int j = 0; j < 8; j++) split_bf(xs[j], hi_.s[j], lo_.s[j]);
    *reinterpret_cast<uint4*>(wpk + (size_t)gid * 8)        = hi_.q;
    *reinterpret_cast<uint4*>(wpk + losz + (size_t)gid * 8) = lo_.q;
}

// ---------------------------------------------------------------- weight prep (wave-contiguous layout, vproj)
// Col permutation for float4 C-writes: slot (nblk, lane=g*16+ln) holds W row
// n = (nblk>>2)*64 + ln*4 + (nblk&3)  -> fragment nt of wave w, lane ln covers
// col w*64 + ln*4 + nt (thread's 4 output cols adjacent).
__global__ __launch_bounds__(256) void k_prepw2(
    const float* __restrict__ Wsrc, ushort* __restrict__ wpk)
{
    int gid = blockIdx.x * 256 + threadIdx.x;   // 8192 slots: (nblk*8+kk)*64+lane
    if (gid >= 8192) return;
    int lane = gid & 63;
    int kk   = (gid >> 6) & 7;
    int nblk = gid >> 9;
    int ln = lane & 15, g = lane >> 4;
    int n = ((nblk >> 2) << 6) + (ln << 2) + (nblk & 3);
    const float* src = Wsrc + (size_t)n * cE + kk * 32 + 4 * g;
    float4 x0 = *reinterpret_cast<const float4*>(src);
    float4 x1 = *reinterpret_cast<const float4*>(src + 16);
    float xs[8] = {x0.x, x0.y, x0.z, x0.w, x1.x, x1.y, x1.z, x1.w};
    union { ushort s[8]; uint4 q; } hi_, lo_;
#pragma unroll
    for (int j = 0; j < 8; j++) split_bf(xs[j], hi_.s[j], lo_.s[j]);
    *reinterpret_cast<uint4*>(wpk + (size_t)gid * 8)         = hi_.q;
    *reinterpret_cast<uint4*>(wpk + 65536 + (size_t)gid * 8) = lo_.q;
}

// ---------------------------------------------------------------- fused vproj GEMM v4 (round-20 best: M-block 64)
// C[160000][256] = A @ W^T + b, row-major C, float4 C-writes (col-permuted W pack).
// Double-buffered global_load_lds staging; one barrier per k-step; rule-#21 XOR
// swizzle on both sides (pre-swizzled global source + swizzled ds_read addrs).
__global__ __launch_bounds__(256) void k_bgemm2(
    const float* __restrict__ A, const ushort* __restrict__ wpk2,
    const float* __restrict__ bias, float* __restrict__ vimg)
{
    __shared__ float lds[2][2048];   // two 64x32 fp32 tiles, linear
    const int t    = threadIdx.x;
    const int w    = t >> 6;
    const int lane = t & 63;
    const int g    = lane >> 4;
    const int ln   = lane & 15;
    const int bm   = blockIdx.x * 64;
    const ushort* wlo = wpk2 + 65536;

    f32x4 acc[4][4];
#pragma unroll
    for (int mt = 0; mt < 4; mt++)
#pragma unroll
        for (int nt = 0; nt < 4; nt++) acc[mt][nt] = {0.f, 0.f, 0.f, 0.f};

#define VSTAGE(buf, kkv) {                                                          \
    int row0_ = (w << 4) + (lane >> 3);                                             \
    int c0_ = ((lane & 7) << 4) ^ ((row0_ & 7) << 4);                               \
    gl_lds16(A + (size_t)(bm + row0_) * cE + (kkv) * 32 + (c0_ >> 2),               \
             &lds[buf][(w << 9)]);                                                  \
    int row1_ = row0_ + 8;                                                          \
    int c1_ = ((lane & 7) << 4) ^ ((row1_ & 7) << 4);                               \
    gl_lds16(A + (size_t)(bm + row1_) * cE + (kkv) * 32 + (c1_ >> 2),               \
             &lds[buf][(w << 9) + 256]);                                            \
}

    VSTAGE(0, 0)
    __syncthreads();

#pragma unroll
    for (int kk = 0; kk < 8; kk++) {
        const int cur = kk & 1;
        if (kk < 7) VSTAGE(cur ^ 1, kk + 1)

        // W fragments (wave-contiguous, L2-resident)
        U8 wh[4], wl[4];
#pragma unroll
        for (int nt = 0; nt < 4; nt++) {
            size_t off = (((size_t)(w * 4 + nt) * 8 + kk) * 64 + lane) * 8;
            *reinterpret_cast<uint4*>(&wh[nt].u[0]) = *reinterpret_cast<const uint4*>(wpk2 + off);
            *reinterpret_cast<uint4*>(&wl[nt].u[0]) = *reinterpret_cast<const uint4*>(wlo + off);
        }

        // A fragments from swizzled LDS, split in-register, MFMA
        const char* lb = (const char*)(&lds[cur][0]);
#pragma unroll
        for (int mt = 0; mt < 4; mt++) {
            int row = mt * 16 + ln;
            int mk = (row & 7) << 4;
            float4 x0 = *reinterpret_cast<const float4*>(lb + row * 128 + ((g * 16) ^ mk));
            float4 x1 = *reinterpret_cast<const float4*>(lb + row * 128 + ((64 + g * 16) ^ mk));
            float xs[8] = {x0.x, x0.y, x0.z, x0.w, x1.x, x1.y, x1.z, x1.w};
            U8 aH, aL;
            union { ushort s[8]; uint u[4]; } hs, ls;
#pragma unroll
            for (int j = 0; j < 8; j++) split_bf(xs[j], hs.s[j], ls.s[j]);
#pragma unroll
            for (int i = 0; i < 4; i++) { aH.u[i] = hs.u[i]; aL.u[i] = ls.u[i]; }
#pragma unroll
            for (int nt = 0; nt < 4; nt++) {
                acc[mt][nt] = __builtin_amdgcn_mfma_f32_16x16x32_bf16(aL.v, wh[nt].v, acc[mt][nt], 0, 0, 0);
                acc[mt][nt] = __builtin_amdgcn_mfma_f32_16x16x32_bf16(aH.v, wl[nt].v, acc[mt][nt], 0, 0, 0);
                acc[mt][nt] = __builtin_amdgcn_mfma_f32_16x16x32_bf16(aH.v, wh[nt].v, acc[mt][nt], 0, 0, 0);
            }
        }
        __syncthreads();   // drains vmcnt(0): next tile's gload_lds complete; reads of lds[cur] done
    }
#undef VSTAGE

    // row-major C write, float4 per (mt,r): cols w*64 + ln*4 + {0,1,2,3}
    const int cb = w * 64 + ln * 4;
    float4 bv4 = *reinterpret_cast<const float4*>(&bias[cb]);
#pragma unroll
    for (int mt = 0; mt < 4; mt++) {
#pragma unroll
        for (int r = 0; r < 4; r++) {
            int gr = bm + mt * 16 + 4 * g + r;
            float4 o;
            o.x = acc[mt][0][r] + bv4.x;
            o.y = acc[mt][1][r] + bv4.y;
            o.z = acc[mt][2][r] + bv4.z;
            o.w = acc[mt][3][r] + bv4.w;
            *reinterpret_cast<float4*>(&vimg[(size_t)gr * cE + cb]) = o;
        }
    }
}

// ---------------------------------------------------------------- off/aw head GEMM: raw[8000][96] = xq @ Wcat^T
__global__ __launch_bounds__(256) void k_oagemm(
    const float* __restrict__ xq, const ushort* __restrict__ wpk,
    float* __restrict__ raw)
{
    const int w    = threadIdx.x >> 6;
    const int lane = threadIdx.x & 63;
    const int g    = lane >> 4;
    const int ln   = lane & 15;
    const int row0 = blockIdx.x * 64 + w * 16;
    const ushort* wlo = wpk + 24576;

    f32x4 acc[6];
#pragma unroll
    for (int nt = 0; nt < 6; nt++) acc[nt] = {0.f, 0.f, 0.f, 0.f};

    for (int kk = 0; kk < 8; kk++) {
        const float* ap = xq + (size_t)(row0 + ln) * cE + kk * 32 + 4 * g;
        float4 u0 = *reinterpret_cast<const float4*>(ap);
        float4 u1 = *reinterpret_cast<const float4*>(ap + 16);
        float xs[8] = {u0.x, u0.y, u0.z, u0.w, u1.x, u1.y, u1.z, u1.w};
        U8 aH, aL;
        union { ushort s[8]; uint u[4]; } hs, ls;
#pragma unroll
        for (int j = 0; j < 8; j++) split_bf(xs[j], hs.s[j], ls.s[j]);
#pragma unroll
        for (int i = 0; i < 4; i++) { aH.u[i] = hs.u[i]; aL.u[i] = ls.u[i]; }
#pragma unroll
        for (int nt = 0; nt < 6; nt++) {
            int n = nt * 16 + ln;
            size_t off = ((size_t)(n * 8 + kk) * 4 + g) * 8;
            U8 wh, wl;
            *reinterpret_cast<uint4*>(&wh.u[0]) = *reinterpret_cast<const uint4*>(wpk + off);
            *reinterpret_cast<uint4*>(&wl.u[0]) = *reinterpret_cast<const uint4*>(wlo + off);
            acc[nt] = __builtin_amdgcn_mfma_f32_16x16x32_bf16(aL.v, wh.v, acc[nt], 0, 0, 0);
            acc[nt] = __builtin_amdgcn_mfma_f32_16x16x32_bf16(aH.v, wl.v, acc[nt], 0, 0, 0);
            acc[nt] = __builtin_amdgcn_mfma_f32_16x16x32_bf16(aH.v, wh.v, acc[nt], 0, 0, 0);
        }
    }

#pragma unroll
    for (int nt = 0; nt < 6; nt++) {
        int n = nt * 16 + ln;
#pragma unroll
        for (int r = 0; r < 4; r++) {
            int row = row0 + 4 * g + r;
            raw[(size_t)row * 96 + n] = acc[nt][r];
        }
    }
}

// ---------------------------------------------------------------- loc/aw postprocess
__global__ __launch_bounds__(256) void k_locaw(
    const float* __restrict__ raw, const float* __restrict__ offb,
    const float* __restrict__ awbias, const float* __restrict__ refp,
    float* __restrict__ locO, float* __restrict__ awO)
{
    int gid = blockIdx.x * 256 + threadIdx.x;   // 8000*96
    if (gid >= NTOK * 96) return;
    int i = gid % 96;
    int tok = gid / 96;
    int q = tok >> 3, b = tok & 7;
    int bq = b * cNQ + q;
    const float* rr = raw + (size_t)tok * 96;
    if (i < 64) {
        int c = i & 1;
        float offv = rr[i] + offb[i];
        float refv = refp[((size_t)b * cNQ + q) * 2 + c];
        float nrm = (c == 0) ? 200.f : 100.f;
        locO[(size_t)bq * 64 + i] = refv + offv / nrm;
    } else {
        int j = i - 64;            // j = h*4+p
        int gbase = j & ~3;
        float x0 = rr[64 + gbase + 0] + awbias[gbase + 0];
        float x1 = rr[64 + gbase + 1] + awbias[gbase + 1];
        float x2 = rr[64 + gbase + 2] + awbias[gbase + 2];
        float x3 = rr[64 + gbase + 3] + awbias[gbase + 3];
        float xm = rr[64 + j] + awbias[j];
        float mx = fmaxf(fmaxf(x0, x1), fmaxf(x2, x3));
        float e = __expf(xm - mx);
        float ssum = __expf(x0 - mx) + __expf(x1 - mx) + __expf(x2 - mx) + __expf(x3 - mx);
        awO[(size_t)bq * 32 + j] = e / ssum;
    }
}

// ---------------------------------------------------------------- unified split-precision MFMA GEMM (small GEMMs)
constexpr int MM_QKV   = 1;
constexpr int MM_PLAIN = 2;
constexpr int MM_RELU  = 3;
constexpr int MM_OPROJ = 4;

template <int MODE, int TKK, int NFULL>
__global__ __launch_bounds__(256) void k_mgemm(
    const float* __restrict__ A, const float* __restrict__ A2,
    const ushort* __restrict__ wpk, int losz,
    const float* __restrict__ bias,
    void* __restrict__ C0, void* __restrict__ C1, void* __restrict__ C2)
{
    const int w    = threadIdx.x >> 6;
    const int lane = threadIdx.x & 63;
    const int g    = lane >> 4;
    const int ln   = lane & 15;
    const int bm   = blockIdx.x * 32;
    const int slab = blockIdx.y;
    const int nb   = slab * 256 + w * 64;
    const ushort* wlo = wpk + losz;
    const int K = TKK * 32;

    f32x4 acc[2][4];
#pragma unroll
    for (int mt = 0; mt < 2; mt++)
#pragma unroll
        for (int nt = 0; nt < 4; nt++) acc[mt][nt] = {0.f, 0.f, 0.f, 0.f};

    U8 wh[2][4], wl[2][4];
    float ax[2][2][8];

#define MG_LOADW(kk, buf) {                                                        \
    _Pragma("unroll")                                                              \
    for (int nt = 0; nt < 4; nt++) {                                               \
        int n = nb + nt * 16 + ln;                                                 \
        size_t off = ((size_t)(n * TKK + (kk)) * 4 + g) * 8;                       \
        *reinterpret_cast<uint4*>(&wh[buf][nt].u[0]) = *reinterpret_cast<const uint4*>(wpk + off); \
        *reinterpret_cast<uint4*>(&wl[buf][nt].u[0]) = *reinterpret_cast<const uint4*>(wlo + off); \
    } }

#define MG_LOADA(kk, buf) {                                                        \
    _Pragma("unroll")                                                              \
    for (int mt = 0; mt < 2; mt++) {                                               \
        const float* ap = A + (size_t)(bm + mt * 16 + ln) * K + (kk) * 32 + 4 * g; \
        float4 u0 = *reinterpret_cast<const float4*>(ap);                          \
        float4 u1 = *reinterpret_cast<const float4*>(ap + 16);                     \
        if (MODE == MM_QKV && slab < 2) {                                          \
            const float* bp = A2 + (size_t)(bm + mt * 16 + ln) * K + (kk) * 32 + 4 * g; \
            float4 v0 = *reinterpret_cast<const float4*>(bp);                      \
            float4 v1 = *reinterpret_cast<const float4*>(bp + 16);                 \
            u0.x += v0.x; u0.y += v0.y; u0.z += v0.z; u0.w += v0.w;                \
            u1.x += v1.x; u1.y += v1.y; u1.z += v1.z; u1.w += v1.w;                \
        }                                                                          \
        ax[buf][mt][0] = u0.x; ax[buf][mt][1] = u0.y;                              \
        ax[buf][mt][2] = u0.z; ax[buf][mt][3] = u0.w;                              \
        ax[buf][mt][4] = u1.x; ax[buf][mt][5] = u1.y;                              \
        ax[buf][mt][6] = u1.z; ax[buf][mt][7] = u1.w;                              \
    } }

#define MG_STEP(buf) {                                                             \
    _Pragma("unroll")                                                              \
    for (int mt = 0; mt < 2; mt++) {                                               \
        U8 aH, aL;                                                                 \
        union { ushort s[8]; uint u[4]; } hs, ls;                                  \
        _Pragma("unroll")                                                          \
        for (int j = 0; j < 8; j++) split_bf(ax[buf][mt][j], hs.s[j], ls.s[j]);    \
        _Pragma("unroll")                                                          \
        for (int i = 0; i < 4; i++) { aH.u[i] = hs.u[i]; aL.u[i] = ls.u[i]; }      \
        _Pragma("unroll")                                                          \
        for (int nt = 0; nt < 4; nt++) {                                           \
            acc[mt][nt] = __builtin_amdgcn_mfma_f32_16x16x32_bf16(aL.v, wh[buf][nt].v, acc[mt][nt], 0, 0, 0); \
            acc[mt][nt] = __builtin_amdgcn_mfma_f32_16x16x32_bf16(aH.v, wl[buf][nt].v, acc[mt][nt], 0, 0, 0); \
            acc[mt][nt] = __builtin_amdgcn_mfma_f32_16x16x32_bf16(aH.v, wh[buf][nt].v, acc[mt][nt], 0, 0, 0); \
        }                                                                          \
    } }

    MG_LOADW(0, 0)
    MG_LOADA(0, 0)
#pragma unroll
    for (int kk = 0; kk < TKK; kk++) {
        if (kk + 1 < TKK) {
            MG_LOADW(kk + 1, (kk + 1) & 1)
            MG_LOADA(kk + 1, (kk + 1) & 1)
        }
        MG_STEP(kk & 1)
    }
#undef MG_LOADW
#undef MG_LOADA
#undef MG_STEP

#pragma unroll
    for (int nt = 0; nt < 4; nt++) {
        int n = nb + nt * 16 + ln;
        float bv = bias[n];
#pragma unroll
        for (int mt = 0; mt < 2; mt++) {
#pragma unroll
            for (int r = 0; r < 4; r++) {
                int gr = bm + mt * 16 + 4 * g + r;
                float val = acc[mt][nt][r] + bv;
                if (MODE == MM_QKV) {
                    int tok = gr >> 3, b = gr & 7;
                    int nloc = n & 255, h = nloc >> 5, d = nloc & 31;
                    if (slab == 0) val *= 0.17677669529663687f; // 1/sqrt(32)
                    ushort hs, ls;
                    split_bf(val, hs, ls);
                    if (slab < 2) {
                        // fragment-contiguous: slot(d) = ((d>>2)&3)*8 + (d&3) + 4*(d>>4)
                        int slot = ((d >> 2) & 3) * 8 + (d & 3) + 4 * (d >> 4);
                        ushort* base = (slab == 0) ? (ushort*)C0 : (ushort*)C1;
                        size_t off = ((size_t)(b * cHH + h) * 1024 + tok) * 32 + slot;
                        base[off]         = hs;
                        base[QKSZ2 + off] = ls;
                    } else {
                        // V: [bh][d][tokblk][slot], slot(o) over tok offset within 32-block
                        int o = tok & 31, kbi = tok >> 5;
                        int slot = ((o >> 2) & 3) * 8 + (o & 3) + 4 * (o >> 4);
                        ushort* vb = (ushort*)C2;
                        size_t off = ((size_t)(b * cHH + h) * 32 + d) * 1024 + kbi * 32 + slot;
                        vb[off]         = hs;
                        vb[QKSZ2 + off] = ls;
                    }
                } else if (MODE == MM_OPROJ) {
                    int b = gr / cNQ, q = gr - b * cNQ;
                    ((float*)C0)[((size_t)q * cBS + b) * cE + n] = val;
                } else {
                    if (MODE == MM_RELU) val = fmaxf(val, 0.f);
                    ((float*)C0)[(size_t)gr * NFULL + n] = val;
                }
            }
        }
    }
}

// ---------------------------------------------------------------- MFMA flash attention (v8: 2x Q-blocking, XCD swizzle, K-split)
__global__ __launch_bounds__(256) void k_attn3(
    const ushort* __restrict__ qhi, const ushort* __restrict__ qlo,
    const ushort* __restrict__ khi, const ushort* __restrict__ klo,
    const ushort* __restrict__ vhi, const ushort* __restrict__ vlo,
    float* __restrict__ po, float* __restrict__ plsum)
{
    const int bid   = blockIdx.x;           // 1024 blocks
    const int xcd   = bid & 7;
    const int inner = bid >> 3;             // 0..127
    const int bh    = ((inner & 7) << 3) + xcd;   // bh % 8 == bid % 8
    const int rest  = inner >> 3;           // 0..15
    const int qbix  = rest & 7;             // q-block of 128 rows
    const int z     = rest >> 3;            // 0..1

    const int w    = threadIdx.x >> 6;
    const int lane = threadIdx.x & 63;
    const int g    = lane >> 4;
    const int ql   = lane & 15;
    const int qA   = qbix * 128 + w * 32;   // wave: rows [qA, qA+16) and [qA+16, qA+32)

    const size_t qoffA = ((size_t)bh * 1024 + qA + ql) * 32 + g * 8;
    U8 bQAh, bQAl, bQBh, bQBl;
    *reinterpret_cast<uint4*>(&bQAh.u[0]) = *reinterpret_cast<const uint4*>(qhi + qoffA);
    *reinterpret_cast<uint4*>(&bQAl.u[0]) = *reinterpret_cast<const uint4*>(qlo + qoffA);
    *reinterpret_cast<uint4*>(&bQBh.u[0]) = *reinterpret_cast<const uint4*>(qhi + qoffA + 16 * 32);
    *reinterpret_cast<uint4*>(&bQBl.u[0]) = *reinterpret_cast<const uint4*>(qlo + qoffA + 16 * 32);
    const size_t koff = ((size_t)bh * 1024 + ql) * 32 + g * 8;
    const size_t voff = ((size_t)bh * 32 + ql) * 1024 + g * 8;

    f32x4 oA0 = {0.f,0.f,0.f,0.f}, oA1 = {0.f,0.f,0.f,0.f};
    f32x4 oB0 = {0.f,0.f,0.f,0.f}, oB1 = {0.f,0.f,0.f,0.f};
    float lpartA = 0.f, lpartB = 0.f;
    const f32x4 zz = {0.f, 0.f, 0.f, 0.f};

    const int kt0 = z * 16;
#pragma unroll
    for (int kti = 0; kti < 16; kti++) {
        const int kt = kt0 + kti;
        U8 k0h, k1h, k0l, k1l, v0h, v1h, v0l, v1l;
        {
            size_t kb32 = (size_t)kt * 32 * 32;
            *reinterpret_cast<uint4*>(&k0h.u[0]) = *reinterpret_cast<const uint4*>(khi + koff + kb32);
            *reinterpret_cast<uint4*>(&k1h.u[0]) = *reinterpret_cast<const uint4*>(khi + koff + kb32 + 512);
            *reinterpret_cast<uint4*>(&k0l.u[0]) = *reinterpret_cast<const uint4*>(klo + koff + kb32);
            *reinterpret_cast<uint4*>(&k1l.u[0]) = *reinterpret_cast<const uint4*>(klo + koff + kb32 + 512);
            size_t vb32 = voff + (size_t)kt * 32;
            *reinterpret_cast<uint4*>(&v0h.u[0]) = *reinterpret_cast<const uint4*>(vhi + vb32);
            *reinterpret_cast<uint4*>(&v1h.u[0]) = *reinterpret_cast<const uint4*>(vhi + vb32 + 16 * 1024);
            *reinterpret_cast<uint4*>(&v0l.u[0]) = *reinterpret_cast<const uint4*>(vlo + vb32);
            *reinterpret_cast<uint4*>(&v1l.u[0]) = *reinterpret_cast<const uint4*>(vlo + vb32 + 16 * 1024);
        }

        const bool tail = (kti == 15) && (z == 1);

        f32x4 sA0 = __builtin_amdgcn_mfma_f32_16x16x32_bf16(k0l.v, bQAh.v, zz, 0, 0, 0);
        sA0 = __builtin_amdgcn_mfma_f32_16x16x32_bf16(k0h.v, bQAl.v, sA0, 0, 0, 0);
        sA0 = __builtin_amdgcn_mfma_f32_16x16x32_bf16(k0h.v, bQAh.v, sA0, 0, 0, 0);
        f32x4 sB0 = __builtin_amdgcn_mfma_f32_16x16x32_bf16(k0l.v, bQBh.v, zz, 0, 0, 0);
        sB0 = __builtin_amdgcn_mfma_f32_16x16x32_bf16(k0h.v, bQBl.v, sB0, 0, 0, 0);
        sB0 = __builtin_amdgcn_mfma_f32_16x16x32_bf16(k0h.v, bQBh.v, sB0, 0, 0, 0);
        f32x4 sA1, sB1;
        if (tail) {
            int tb = 31 * 32 + 4 * g;
#pragma unroll
            for (int r = 0; r < 4; r++) {
                if (tb + r >= cNQ) { sA0[r] = -INFINITY; sB0[r] = -INFINITY; }
            }
            sA1[0] = sA1[1] = sA1[2] = sA1[3] = -INFINITY;
            sB1[0] = sB1[1] = sB1[2] = sB1[3] = -INFINITY;
        } else {
            sA1 = __builtin_amdgcn_mfma_f32_16x16x32_bf16(k1l.v, bQAh.v, zz, 0, 0, 0);
            sA1 = __builtin_amdgcn_mfma_f32_16x16x32_bf16(k1h.v, bQAl.v, sA1, 0, 0, 0);
            sA1 = __builtin_amdgcn_mfma_f32_16x16x32_bf16(k1h.v, bQAh.v, sA1, 0, 0, 0);
            sB1 = __builtin_amdgcn_mfma_f32_16x16x32_bf16(k1l.v, bQBh.v, zz, 0, 0, 0);
            sB1 = __builtin_amdgcn_mfma_f32_16x16x32_bf16(k1h.v, bQBl.v, sB1, 0, 0, 0);
            sB1 = __builtin_amdgcn_mfma_f32_16x16x32_bf16(k1h.v, bQBh.v, sB1, 0, 0, 0);
        }

        float pA00 = __expf(sA0[0]), pA01 = __expf(sA0[1]);
        float pA02 = __expf(sA0[2]), pA03 = __expf(sA0[3]);
        float pA10 = __expf(sA1[0]), pA11 = __expf(sA1[1]);
        float pA12 = __expf(sA1[2]), pA13 = __expf(sA1[3]);
        lpartA += ((pA00 + pA01) + (pA02 + pA03)) + ((pA10 + pA11) + (pA12 + pA13));
        float pB00 = __expf(sB0[0]), pB01 = __expf(sB0[1]);
        float pB02 = __expf(sB0[2]), pB03 = __expf(sB0[3]);
        float pB10 = __expf(sB1[0]), pB11 = __expf(sB1[1]);
        float pB12 = __expf(sB1[2]), pB13 = __expf(sB1[3]);
        lpartB += ((pB00 + pB01) + (pB02 + pB03)) + ((pB10 + pB11) + (pB12 + pB13));

        U8 fpAh, fpAl, fpBh, fpBl;
        pk_split2(pA00, pA01, fpAh.u[0], fpAl.u[0]);
        pk_split2(pA02, pA03, fpAh.u[1], fpAl.u[1]);
        pk_split2(pA10, pA11, fpAh.u[2], fpAl.u[2]);
        pk_split2(pA12, pA13, fpAh.u[3], fpAl.u[3]);
        pk_split2(pB00, pB01, fpBh.u[0], fpBl.u[0]);
        pk_split2(pB02, pB03, fpBh.u[1], fpBl.u[1]);
        pk_split2(pB10, pB11, fpBh.u[2], fpBl.u[2]);
        pk_split2(pB12, pB13, fpBh.u[3], fpBl.u[3]);

        oA0 = __builtin_amdgcn_mfma_f32_16x16x32_bf16(v0l.v, fpAh.v, oA0, 0, 0, 0);
        oA0 = __builtin_amdgcn_mfma_f32_16x16x32_bf16(v0h.v, fpAl.v, oA0, 0, 0, 0);
        oA0 = __builtin_amdgcn_mfma_f32_16x16x32_bf16(v0h.v, fpAh.v, oA0, 0, 0, 0);
        oA1 = __builtin_amdgcn_mfma_f32_16x16x32_bf16(v1l.v, fpAh.v, oA1, 0, 0, 0);
        oA1 = __builtin_amdgcn_mfma_f32_16x16x32_bf16(v1h.v, fpAl.v, oA1, 0, 0, 0);
        oA1 = __builtin_amdgcn_mfma_f32_16x16x32_bf16(v1h.v, fpAh.v, oA1, 0, 0, 0);
        oB0 = __builtin_amdgcn_mfma_f32_16x16x32_bf16(v0l.v, fpBh.v, oB0, 0, 0, 0);
        oB0 = __builtin_amdgcn_mfma_f32_16x16x32_bf16(v0h.v, fpBl.v, oB0, 0, 0, 0);
        oB0 = __builtin_amdgcn_mfma_f32_16x16x32_bf16(v0h.v, fpBh.v, oB0, 0, 0, 0);
        oB1 = __builtin_amdgcn_mfma_f32_16x16x32_bf16(v1l.v, fpBh.v, oB1, 0, 0, 0);
        oB1 = __builtin_amdgcn_mfma_f32_16x16x32_bf16(v1h.v, fpBl.v, oB1, 0, 0, 0);
        oB1 = __builtin_amdgcn_mfma_f32_16x16x32_bf16(v1h.v, fpBh.v, oB1, 0, 0, 0);
    }

    // per-lane partial denominators -> per-q via 2 xor-shfls (same q across g groups)
    float lsumA = lpartA;
    lsumA += __shfl_xor(lsumA, 16, 64);
    lsumA += __shfl_xor(lsumA, 32, 64);
    float lsumB = lpartB;
    lsumB += __shfl_xor(lsumB, 16, 64);
    lsumB += __shfl_xor(lsumB, 32, 64);

    {
        const int q = qA + ql;
        if (q < cNQ) {
            size_t base = ((size_t)(z * 64 + bh) * 1000 + q) * 32;
            float4 v0, v1;
            v0.x = oA0[0]; v0.y = oA0[1]; v0.z = oA0[2]; v0.w = oA0[3];
            v1.x = oA1[0]; v1.y = oA1[1]; v1.z = oA1[2]; v1.w = oA1[3];
            *reinterpret_cast<float4*>(po + base + 4 * g)      = v0;
            *reinterpret_cast<float4*>(po + base + 16 + 4 * g) = v1;
            if (g == 0) plsum[(size_t)(z * 64 + bh) * 1000 + q] = lsumA;
        }
    }
    {
        const int q = qA + 16 + ql;
        if (q < cNQ) {
            size_t base = ((size_t)(z * 64 + bh) * 1000 + q) * 32;
            float4 v0, v1;
            v0.x = oB0[0]; v0.y = oB0[1]; v0.z = oB0[2]; v0.w = oB0[3];
            v1.x = oB1[0]; v1.y = oB1[1]; v1.z = oB1[2]; v1.w = oB1[3];
            *reinterpret_cast<float4*>(po + base + 4 * g)      = v0;
            *reinterpret_cast<float4*>(po + base + 16 + 4 * g) = v1;
            if (g == 0) plsum[(size_t)(z * 64 + bh) * 1000 + q] = lsumB;
        }
    }
}

// ---------------------------------------------------------------- attention partial reduce
__global__ __launch_bounds__(256) void k_ared(
    const float* __restrict__ po, const float* __restrict__ plsum,
    float* __restrict__ outp)
{
    int gid = blockIdx.x * 256 + threadIdx.x;   // 64*1000*32 = 2,048,000
    if (gid >= 64 * 1000 * 32) return;
    int d   = gid & 31;
    int rem = gid >> 5;         // bh*1000 + q
    int q   = rem % 1000;
    int bh  = rem / 1000;
    float o = po[gid] + po[(size_t)64 * 1000 * 32 + gid];
    float l = plsum[rem] + plsum[64000 + rem];
    int b = bh >> 3, h = bh & 7;
    outp[((size_t)q * cBS + b) * cE + h * 32 + d] = o / l;
}

// ---------------------------------------------------------------- layernorm
__global__ __launch_bounds__(256) void k_ln(
    const float* __restrict__ a, const float* __restrict__ b,
    const float* __restrict__ w, const float* __restrict__ bias,
    const float* __restrict__ addc,
    float* __restrict__ outp, float* __restrict__ out2)
{
    int rrow = blockIdx.x, t = threadIdx.x;
    size_t base = (size_t)rrow * cE;
    float v = a[base + t] + b[base + t];
    float s = v;
#pragma unroll
    for (int off = 32; off > 0; off >>= 1) s += __shfl_down(s, off, 64);
    __shared__ float red1[4], red2[4];
    int wid = t >> 6, lane = t & 63;
    if (lane == 0) red1[wid] = s;
    __syncthreads();
    float mu = (red1[0] + red1[1] + red1[2] + red1[3]) * (1.f / cE);
    float e = v - mu;
    float s2 = e * e;
#pragma unroll
    for (int off = 32; off > 0; off >>= 1) s2 += __shfl_down(s2, off, 64);
    if (lane == 0) red2[wid] = s2;
    __syncthreads();
    float var = (red2[0] + red2[1] + red2[2] + red2[3]) * (1.f / cE);
    float y = e * (1.f / sqrtf(var + 1e-5f)) * w[t] + bias[t];
    outp[base + t] = y;
    if (out2 != nullptr) out2[base + t] = y + addc[base + t];
}

// ---------------------------------------------------------------- MSDA sampling (vimg row-major [tok][E], tok = nv*BS + b)
__device__ __forceinline__ float samp_one(const float* __restrict__ img, int x, int y)
{
    bool ok = (x >= 0) & (x < cW) & (y >= 0) & (y < cH);
    int xc = min(max(x, 0), cW - 1);
    int yc = min(max(y, 0), cH - 1);
    float v = img[(size_t)(yc * cW + xc) * (cBS * cE)];
    return ok ? v : 0.f;
}

__global__ __launch_bounds__(256) void k_msda(
    const float* __restrict__ vimg, const float* __restrict__ loc,
    const float* __restrict__ aw, float* __restrict__ msp)
{
    int gid = blockIdx.x * 256 + threadIdx.x;
    int d  = gid & 31;
    int h  = (gid >> 5) & 7;
    int bq = gid >> 8;
    int b  = bq / cNQ;
    const float* lp = loc + ((size_t)bq * cHH + h) * (cP * 2);
    const float* ap = aw + ((size_t)bq * cHH + h) * cP;
    const float* img = vimg + (size_t)b * cE + h * cDH + d;
    float acc = 0.f;
#pragma unroll
    for (int p = 0; p < cP; p++) {
        float g0 = 2.f * lp[p * 2 + 0] - 1.f;
        float g1 = 2.f * lp[p * 2 + 1] - 1.f;
        float xf = (g0 + 1.f) * 0.5f * (float)cW - 0.5f;
        float yf = (g1 + 1.f) * 0.5f * (float)cH - 0.5f;
        float x0f = floorf(xf), y0f = floorf(yf);
        float wx = xf - x0f, wy = yf - y0f;
        int x0 = (int)x0f, y0 = (int)y0f;
        float v00 = samp_one(img, x0,     y0);
        float v01 = samp_one(img, x0 + 1, y0);
        float v10 = samp_one(img, x0,     y0 + 1);
        float v11 = samp_one(img, x0 + 1, y0 + 1);
        float bil = v00 * (1.f - wx) * (1.f - wy) + v01 * wx * (1.f - wy)
                  + v10 * (1.f - wx) * wy        + v11 * wx * wy;
        acc = fmaf(bil, ap[p], acc);
    }
    msp[gid] = acc;
}

// ---------------------------------------------------------------- launch
extern "C" void kernel_launch(void* const* d_in, const int* in_sizes, int n_in,
                              void* d_out, int out_size, void* d_ws, size_t ws_size,
                              hipStream_t stream)
{
    const float* query = (const float*)d_in[0];
    const float* qpos  = (const float*)d_in[1];
    const float* value = (const float*)d_in[2];
    const float* refp  = (const float*)d_in[3];
    const float* inw   = (const float*)d_in[4];
    const float* inb   = (const float*)d_in[5];
    const float* outw  = (const float*)d_in[6];
    const float* outb  = (const float*)d_in[7];
    const float* ln1w  = (const float*)d_in[8];
    const float* ln1b  = (const float*)d_in[9];
    const float* ln2w  = (const float*)d_in[10];
    const float* ln2b  = (const float*)d_in[11];
    const float* ln3w  = (const float*)d_in[12];
    const float* ln3b  = (const float*)d_in[13];
    const float* offw  = (const float*)d_in[14];
    const float* offb  = (const float*)d_in[15];
    const float* aww   = (const float*)d_in[16];
    const float* awbias= (const float*)d_in[17];
    const float* vpw   = (const float*)d_in[18];
    const float* vpb   = (const float*)d_in[19];
    const float* opw   = (const float*)d_in[20];
    const float* opb   = (const float*)d_in[21];
    const float* f1w   = (const float*)d_in[22];
    const float* f1b   = (const float*)d_in[23];
    const float* f2w   = (const float*)d_in[24];
    const float* f2b   = (const float*)d_in[25];
    float* out = (float*)d_out;

    float* ws = (float*)d_ws;
    const size_t S = (size_t)NTOK * cE;              // 2,048,000 floats
    const size_t BPADF = 6 * QKSZ2 / 2;              // 6,291,456 floats
    const size_t WPKF = 655360 + 24576;              // packed weights
    const size_t PLS  = 128000;                      // plsum[2][64][1000]
    const size_t need = 2 * S + BPADF + 512000 + 256000 + WPKF + PLS + (size_t)cBS * cHH * cNV * cDH;
    if (ws_size < need * sizeof(float)) return;

    float* P0   = ws;
    float* P1   = ws + S;
    float* Bpad = ws + 2 * S;
    float* locb = Bpad + BPADF;
    float* awb2 = locb + 512000;
    float* wpkf = awb2 + 256000;
    float* plsb = wpkf + WPKF;
    float* vimg = plsb + PLS;

    ushort* qhi = (ushort*)Bpad;
    ushort* qlo = qhi + QKSZ2;
    ushort* khi = qhi + 2 * QKSZ2;
    ushort* klo = qhi + 3 * QKSZ2;
    ushort* vhi = qhi + 4 * QKSZ2;
    ushort* vlo = qhi + 5 * QKSZ2;

    ushort* wpk_vp = (ushort*)wpkf;            // 131072 (wave-contiguous: hi 65536 + lo)
    ushort* wpk_in = wpk_vp + 131072;          // 393216
    ushort* wpk_ou = wpk_in + 393216;          // 131072
    ushort* wpk_op = wpk_ou + 131072;          // 131072
    ushort* wpk_f1 = wpk_op + 131072;          // 262144
    ushort* wpk_f2 = wpk_f1 + 262144;          // 262144
    ushort* wpk_oa = wpk_f2 + 262144;          // 49152 (96 rows: hi 24576 + lo)

    // pack weights
    k_prepw2<<<dim3(32), dim3(256), 0, stream>>>(vpw, wpk_vp);
    k_prepw<<<dim3(96), dim3(256), 0, stream>>>(inw,  wpk_in, 8,  24576, 196608);
    k_prepw<<<dim3(32), dim3(256), 0, stream>>>(outw, wpk_ou, 8,  8192,  65536);
    k_prepw<<<dim3(32), dim3(256), 0, stream>>>(opw,  wpk_op, 8,  8192,  65536);
    k_prepw<<<dim3(64), dim3(256), 0, stream>>>(f1w,  wpk_f1, 8,  16384, 131072);
    k_prepw<<<dim3(64), dim3(256), 0, stream>>>(f2w,  wpk_f2, 16, 16384, 131072);
    k_prepw<<<dim3(8),  dim3(256), 0, stream>>>(offw, wpk_oa, 8,  2048,  24576);
    k_prepw<<<dim3(4),  dim3(256), 0, stream>>>(aww,  wpk_oa + 16384, 8, 1024, 24576);

    // value projection: fused gload_lds-pipelined split + MFMA GEMM, float4 C-writes
    k_bgemm2<<<dim3(2500), dim3(256), 0, stream>>>(value, wpk_vp, vpb, vimg);

    // zero V pad region (unwritten slots must be finite; 0*p=0)
    k_zerou4<<<dim3(2048), dim3(256), 0, stream>>>(
        reinterpret_cast<uint4*>(vhi), (int)(2 * QKSZ2 * 2 / 16));

    // QKV projection (q,k from query+qpos fused; v from query) -> fragment-contiguous bf16 hi/lo
    k_mgemm<MM_QKV, 8, 768><<<dim3(250, 3), dim3(256), 0, stream>>>(
        query, qpos, wpk_in, 196608, inb, qhi, khi, vhi);

    // split-precision MFMA flash attention, 2x Q-blocked, 2-way K-split, XCD-swizzled
    k_attn3<<<dim3(1024), dim3(256), 0, stream>>>(
        qhi, qlo, khi, klo, vhi, vlo, P0, plsb);

    // combine partials -> attn_pre (qhi/qlo region of Bpad, dead after attn3)
    float* attn_pre = Bpad;
    k_ared<<<dim3(8000), dim3(256), 0, stream>>>(P0, plsb, attn_pre);

    // out-proj
    float* mha_y = P1;
    k_mgemm<MM_PLAIN, 8, 256><<<dim3(250, 1), dim3(256), 0, stream>>>(
        attn_pre, nullptr, wpk_ou, 65536, outb, mha_y, nullptr, nullptr);

    // LN1: x = LN(query + mha_y), xq = x + query_pos
    float* x  = Bpad;
    float* xq = Bpad + S;
    k_ln<<<dim3(NTOK), dim3(256), 0, stream>>>(query, mha_y, ln1w, ln1b, qpos, x, xq);

    // off/aw head: GEMM (raw = xq @ Wcat^T) + loc/softmax postprocess
    float* rawb = P0;
    k_oagemm<<<dim3(125), dim3(256), 0, stream>>>(xq, wpk_oa, rawb);
    k_locaw<<<dim3((NTOK * 96 + 255) / 256), dim3(256), 0, stream>>>(
        rawb, offb, awbias, refp, locb, awb2);

    // MSDA bilinear sample
    float* ms_pre = P1;
    k_msda<<<dim3(NTOK * cE / 256), dim3(256), 0, stream>>>(vimg, locb, awb2, ms_pre);

    // oproj (rows (b,q) -> write (q,b))
    float* ms_y = P0;
    k_mgemm<MM_OPROJ, 8, 256><<<dim3(250, 1), dim3(256), 0, stream>>>(
        ms_pre, nullptr, wpk_op, 65536, opb, ms_y, nullptr, nullptr);

    // LN2: x2 = LN(x + ms_y)
    float* x2 = Bpad + 2 * S;
    k_ln<<<dim3(NTOK), dim3(256), 0, stream>>>(x, ms_y, ln2w, ln2b, nullptr, x2, nullptr);

    // FFN (hbuf reuses Bpad[0..2S) — x/xq dead)
    float* hbuf = Bpad;
    k_mgemm<MM_RELU, 8, 512><<<dim3(250, 2), dim3(256), 0, stream>>>(
        x2, nullptr, wpk_f1, 131072, f1b, hbuf, nullptr, nullptr);
    float* y3 = P0;
    k_mgemm<MM_PLAIN, 16, 256><<<dim3(250, 1), dim3(256), 0, stream>>>(
        hbuf, nullptr, wpk_f2, 131072, f2b, y3, nullptr, nullptr);

    // LN3 -> out
    k_ln<<<dim3(NTOK), dim3(256), 0, stream>>>(x2, y3, ln3w, ln3b, nullptr, out, nullptr);
}

// Round 23
// 408.820 us; speedup vs baseline: 1.0914x; 1.0028x over previous
//
#include <hip/hip_runtime.h>
#include <hip/hip_bf16.h>
#include <cmath>

constexpr int cBS = 8;
constexpr int cNQ = 1000;
constexpr int cNV = 20000;
constexpr int cE  = 256;
constexpr int cHH = 8;
constexpr int cDH = 32;
constexpr int cP  = 4;
constexpr int cFFN = 512;
constexpr int cH = 100;
constexpr int cW = 200;
constexpr int NTOK = cNQ * cBS;   // 8000
constexpr size_t QKSZ2 = (size_t)64 * 1024 * cDH;  // 2,097,152 ushorts per padded bf16 buffer

typedef float f32x4 __attribute__((ext_vector_type(4)));
typedef short bf16x8 __attribute__((ext_vector_type(8)));
union U8 { uint u[4]; bf16x8 v; };

__device__ __forceinline__ void split_bf(float x, ushort& h, ushort& l) {
    __hip_bfloat16 hb = __float2bfloat16(x);
    float hf = __bfloat162float(hb);
    __hip_bfloat16 lb = __float2bfloat16(x - hf);
    h = *reinterpret_cast<ushort*>(&hb);
    l = *reinterpret_cast<ushort*>(&lb);
}
__device__ __forceinline__ void pk_split2(float a, float b, uint& h, uint& l) {
    __hip_bfloat16 ah = __float2bfloat16(a), bh = __float2bfloat16(b);
    float arf = a - __bfloat162float(ah), brf = b - __bfloat162float(bh);
    __hip_bfloat16 al = __float2bfloat16(arf), bl = __float2bfloat16(brf);
    h = ((uint)*reinterpret_cast<ushort*>(&bh) << 16) | *reinterpret_cast<ushort*>(&ah);
    l = ((uint)*reinterpret_cast<ushort*>(&bl) << 16) | *reinterpret_cast<ushort*>(&al);
}

__device__ __forceinline__ void gl_lds16(const float* g, float* l) {
    __builtin_amdgcn_global_load_lds(
        (const __attribute__((address_space(1))) unsigned int*)g,
        (__attribute__((address_space(3))) unsigned int*)l,
        16, 0, 0);
}

// zero ONLY the unwritten V-pad region: kbi=31 block (tok 1000..1023) per (bh,d)
// row, hi+lo buffers. QKV later overwrites the valid slots (tok 992..999) inside.
__global__ __launch_bounds__(256) void k_zerovpad(ushort* __restrict__ vhi)
{
    int i = blockIdx.x * 256 + threadIdx.x;   // 4096 rows: [buf][bh*32+d]
    if (i >= 4096) return;
    int bhd = i & 2047;
    int buf = i >> 11;
    ushort* p = vhi + (size_t)buf * QKSZ2 + (size_t)bhd * 1024 + 31 * 32;
    uint4 z = {0u, 0u, 0u, 0u};
    *reinterpret_cast<uint4*>(p)      = z;
    *reinterpret_cast<uint4*>(p + 8)  = z;
    *reinterpret_cast<uint4*>(p + 16) = z;
    *reinterpret_cast<uint4*>(p + 24) = z;
}

// ---------------------------------------------------------------- weight prep (per-lane fragment layout)
__global__ __launch_bounds__(256) void k_prepw(
    const float* __restrict__ Wsrc, ushort* __restrict__ wpk,
    int nkk /* K/32 */, int total /* N*4*nkk */, int losz /* N*K elems */)
{
    int gid = blockIdx.x * 256 + threadIdx.x;
    if (gid >= total) return;
    int g  = gid & 3;
    int kk = (gid >> 2) % nkk;
    int n  = gid / (4 * nkk);
    const float* src = Wsrc + (size_t)n * (nkk * 32) + kk * 32 + 4 * g;
    float4 x0 = *reinterpret_cast<const float4*>(src);
    float4 x1 = *reinterpret_cast<const float4*>(src + 16);
    float xs[8] = {x0.x, x0.y, x0.z, x0.w, x1.x, x1.y, x1.z, x1.w};
    union { ushort s[8]; uint4 q; } hi_, lo_;
#pragma unroll
    for (int j = 0; j < 8; j++) split_bf(xs[j], hi_.s[j], lo_.s[j]);
    *reinterpret_cast<uint4*>(wpk + (size_t)gid * 8)        = hi_.q;
    *reinterpret_cast<uint4*>(wpk + losz + (size_t)gid * 8) = lo_.q;
}

// ---------------------------------------------------------------- weight prep (wave-contiguous layout, vproj)
// Col permutation for float4 C-writes: slot (nblk, lane=g*16+ln) holds W row
// n = (nblk>>2)*64 + ln*4 + (nblk&3)  -> fragment nt of wave w, lane ln covers
// col w*64 + ln*4 + nt (thread's 4 output cols adjacent).
__global__ __launch_bounds__(256) void k_prepw2(
    const float* __restrict__ Wsrc, ushort* __restrict__ wpk)
{
    int gid = blockIdx.x * 256 + threadIdx.x;   // 8192 slots: (nblk*8+kk)*64+lane
    if (gid >= 8192) return;
    int lane = gid & 63;
    int kk   = (gid >> 6) & 7;
    int nblk = gid >> 9;
    int ln = lane & 15, g = lane >> 4;
    int n = ((nblk >> 2) << 6) + (ln << 2) + (nblk & 3);
    const float* src = Wsrc + (size_t)n * cE + kk * 32 + 4 * g;
    float4 x0 = *reinterpret_cast<const float4*>(src);
    float4 x1 = *reinterpret_cast<const float4*>(src + 16);
    float xs[8] = {x0.x, x0.y, x0.z, x0.w, x1.x, x1.y, x1.z, x1.w};
    union { ushort s[8]; uint4 q; } hi_, lo_;
#pragma unroll
    for (int j = 0; j < 8; j++) split_bf(xs[j], hi_.s[j], lo_.s[j]);
    *reinterpret_cast<uint4*>(wpk + (size_t)gid * 8)         = hi_.q;
    *reinterpret_cast<uint4*>(wpk + 65536 + (size_t)gid * 8) = lo_.q;
}

// ---------------------------------------------------------------- fused vproj GEMM v4 (round-20 best: M-block 64)
// C[160000][256] = A @ W^T + b, row-major C, float4 C-writes (col-permuted W pack).
// Double-buffered global_load_lds staging; one barrier per k-step; rule-#21 XOR
// swizzle on both sides (pre-swizzled global source + swizzled ds_read addrs).
__global__ __launch_bounds__(256) void k_bgemm2(
    const float* __restrict__ A, const ushort* __restrict__ wpk2,
    const float* __restrict__ bias, float* __restrict__ vimg)
{
    __shared__ float lds[2][2048];   // two 64x32 fp32 tiles, linear
    const int t    = threadIdx.x;
    const int w    = t >> 6;
    const int lane = t & 63;
    const int g    = lane >> 4;
    const int ln   = lane & 15;
    const int bm   = blockIdx.x * 64;
    const ushort* wlo = wpk2 + 65536;

    f32x4 acc[4][4];
#pragma unroll
    for (int mt = 0; mt < 4; mt++)
#pragma unroll
        for (int nt = 0; nt < 4; nt++) acc[mt][nt] = {0.f, 0.f, 0.f, 0.f};

#define VSTAGE(buf, kkv) {                                                          \
    int row0_ = (w << 4) + (lane >> 3);                                             \
    int c0_ = ((lane & 7) << 4) ^ ((row0_ & 7) << 4);                               \
    gl_lds16(A + (size_t)(bm + row0_) * cE + (kkv) * 32 + (c0_ >> 2),               \
             &lds[buf][(w << 9)]);                                                  \
    int row1_ = row0_ + 8;                                                          \
    int c1_ = ((lane & 7) << 4) ^ ((row1_ & 7) << 4);                               \
    gl_lds16(A + (size_t)(bm + row1_) * cE + (kkv) * 32 + (c1_ >> 2),               \
             &lds[buf][(w << 9) + 256]);                                            \
}

    VSTAGE(0, 0)
    __syncthreads();

#pragma unroll
    for (int kk = 0; kk < 8; kk++) {
        const int cur = kk & 1;
        if (kk < 7) VSTAGE(cur ^ 1, kk + 1)

        // W fragments (wave-contiguous, L2-resident)
        U8 wh[4], wl[4];
#pragma unroll
        for (int nt = 0; nt < 4; nt++) {
            size_t off = (((size_t)(w * 4 + nt) * 8 + kk) * 64 + lane) * 8;
            *reinterpret_cast<uint4*>(&wh[nt].u[0]) = *reinterpret_cast<const uint4*>(wpk2 + off);
            *reinterpret_cast<uint4*>(&wl[nt].u[0]) = *reinterpret_cast<const uint4*>(wlo + off);
        }

        // A fragments from swizzled LDS, split in-register, MFMA
        const char* lb = (const char*)(&lds[cur][0]);
#pragma unroll
        for (int mt = 0; mt < 4; mt++) {
            int row = mt * 16 + ln;
            int mk = (row & 7) << 4;
            float4 x0 = *reinterpret_cast<const float4*>(lb + row * 128 + ((g * 16) ^ mk));
            float4 x1 = *reinterpret_cast<const float4*>(lb + row * 128 + ((64 + g * 16) ^ mk));
            float xs[8] = {x0.x, x0.y, x0.z, x0.w, x1.x, x1.y, x1.z, x1.w};
            U8 aH, aL;
            union { ushort s[8]; uint u[4]; } hs, ls;
#pragma unroll
            for (int j = 0; j < 8; j++) split_bf(xs[j], hs.s[j], ls.s[j]);
#pragma unroll
            for (int i = 0; i < 4; i++) { aH.u[i] = hs.u[i]; aL.u[i] = ls.u[i]; }
#pragma unroll
            for (int nt = 0; nt < 4; nt++) {
                acc[mt][nt] = __builtin_amdgcn_mfma_f32_16x16x32_bf16(aL.v, wh[nt].v, acc[mt][nt], 0, 0, 0);
                acc[mt][nt] = __builtin_amdgcn_mfma_f32_16x16x32_bf16(aH.v, wl[nt].v, acc[mt][nt], 0, 0, 0);
                acc[mt][nt] = __builtin_amdgcn_mfma_f32_16x16x32_bf16(aH.v, wh[nt].v, acc[mt][nt], 0, 0, 0);
            }
        }
        __syncthreads();   // drains vmcnt(0): next tile's gload_lds complete; reads of lds[cur] done
    }
#undef VSTAGE

    // row-major C write, float4 per (mt,r): cols w*64 + ln*4 + {0,1,2,3}
    const int cb = w * 64 + ln * 4;
    float4 bv4 = *reinterpret_cast<const float4*>(&bias[cb]);
#pragma unroll
    for (int mt = 0; mt < 4; mt++) {
#pragma unroll
        for (int r = 0; r < 4; r++) {
            int gr = bm + mt * 16 + 4 * g + r;
            float4 o;
            o.x = acc[mt][0][r] + bv4.x;
            o.y = acc[mt][1][r] + bv4.y;
            o.z = acc[mt][2][r] + bv4.z;
            o.w = acc[mt][3][r] + bv4.w;
            *reinterpret_cast<float4*>(&vimg[(size_t)gr * cE + cb]) = o;
        }
    }
}

// ---------------------------------------------------------------- off/aw head GEMM: raw[8000][96] = xq @ Wcat^T
__global__ __launch_bounds__(256) void k_oagemm(
    const float* __restrict__ xq, const ushort* __restrict__ wpk,
    float* __restrict__ raw)
{
    const int w    = threadIdx.x >> 6;
    const int lane = threadIdx.x & 63;
    const int g    = lane >> 4;
    const int ln   = lane & 15;
    const int row0 = blockIdx.x * 64 + w * 16;
    const ushort* wlo = wpk + 24576;

    f32x4 acc[6];
#pragma unroll
    for (int nt = 0; nt < 6; nt++) acc[nt] = {0.f, 0.f, 0.f, 0.f};

    for (int kk = 0; kk < 8; kk++) {
        const float* ap = xq + (size_t)(row0 + ln) * cE + kk * 32 + 4 * g;
        float4 u0 = *reinterpret_cast<const float4*>(ap);
        float4 u1 = *reinterpret_cast<const float4*>(ap + 16);
        float xs[8] = {u0.x, u0.y, u0.z, u0.w, u1.x, u1.y, u1.z, u1.w};
        U8 aH, aL;
        union { ushort s[8]; uint u[4]; } hs, ls;
#pragma unroll
        for (int j = 0; j < 8; j++) split_bf(xs[j], hs.s[j], ls.s[j]);
#pragma unroll
        for (int i = 0; i < 4; i++) { aH.u[i] = hs.u[i]; aL.u[i] = ls.u[i]; }
#pragma unroll
        for (int nt = 0; nt < 6; nt++) {
            int n = nt * 16 + ln;
            size_t off = ((size_t)(n * 8 + kk) * 4 + g) * 8;
            U8 wh, wl;
            *reinterpret_cast<uint4*>(&wh.u[0]) = *reinterpret_cast<const uint4*>(wpk + off);
            *reinterpret_cast<uint4*>(&wl.u[0]) = *reinterpret_cast<const uint4*>(wlo + off);
            acc[nt] = __builtin_amdgcn_mfma_f32_16x16x32_bf16(aL.v, wh.v, acc[nt], 0, 0, 0);
            acc[nt] = __builtin_amdgcn_mfma_f32_16x16x32_bf16(aH.v, wl.v, acc[nt], 0, 0, 0);
            acc[nt] = __builtin_amdgcn_mfma_f32_16x16x32_bf16(aH.v, wh.v, acc[nt], 0, 0, 0);
        }
    }

#pragma unroll
    for (int nt = 0; nt < 6; nt++) {
        int n = nt * 16 + ln;
#pragma unroll
        for (int r = 0; r < 4; r++) {
            int row = row0 + 4 * g + r;
            raw[(size_t)row * 96 + n] = acc[nt][r];
        }
    }
}

// ---------------------------------------------------------------- loc/aw postprocess
__global__ __launch_bounds__(256) void k_locaw(
    const float* __restrict__ raw, const float* __restrict__ offb,
    const float* __restrict__ awbias, const float* __restrict__ refp,
    float* __restrict__ locO, float* __restrict__ awO)
{
    int gid = blockIdx.x * 256 + threadIdx.x;   // 8000*96
    if (gid >= NTOK * 96) return;
    int i = gid % 96;
    int tok = gid / 96;
    int q = tok >> 3, b = tok & 7;
    int bq = b * cNQ + q;
    const float* rr = raw + (size_t)tok * 96;
    if (i < 64) {
        int c = i & 1;
        float offv = rr[i] + offb[i];
        float refv = refp[((size_t)b * cNQ + q) * 2 + c];
        float nrm = (c == 0) ? 200.f : 100.f;
        locO[(size_t)bq * 64 + i] = refv + offv / nrm;
    } else {
        int j = i - 64;            // j = h*4+p
        int gbase = j & ~3;
        float x0 = rr[64 + gbase + 0] + awbias[gbase + 0];
        float x1 = rr[64 + gbase + 1] + awbias[gbase + 1];
        float x2 = rr[64 + gbase + 2] + awbias[gbase + 2];
        float x3 = rr[64 + gbase + 3] + awbias[gbase + 3];
        float xm = rr[64 + j] + awbias[j];
        float mx = fmaxf(fmaxf(x0, x1), fmaxf(x2, x3));
        float e = __expf(xm - mx);
        float ssum = __expf(x0 - mx) + __expf(x1 - mx) + __expf(x2 - mx) + __expf(x3 - mx);
        awO[(size_t)bq * 32 + j] = e / ssum;
    }
}

// ---------------------------------------------------------------- unified split-precision MFMA GEMM (small GEMMs)
constexpr int MM_QKV   = 1;
constexpr int MM_PLAIN = 2;
constexpr int MM_RELU  = 3;
constexpr int MM_OPROJ = 4;
constexpr int MM_ARED  = 5;   // fused attn-partial-combine + out-proj: A = po partials, A2 = plsum

template <int MODE, int TKK, int NFULL>
__global__ __launch_bounds__(256) void k_mgemm(
    const float* __restrict__ A, const float* __restrict__ A2,
    const ushort* __restrict__ wpk, int losz,
    const float* __restrict__ bias,
    void* __restrict__ C0, void* __restrict__ C1, void* __restrict__ C2)
{
    const int w    = threadIdx.x >> 6;
    const int lane = threadIdx.x & 63;
    const int g    = lane >> 4;
    const int ln   = lane & 15;
    const int bm   = blockIdx.x * 32;
    const int slab = blockIdx.y;
    const int nb   = slab * 256 + w * 64;
    const ushort* wlo = wpk + losz;
    const int K = TKK * 32;

    f32x4 acc[2][4];
#pragma unroll
    for (int mt = 0; mt < 2; mt++)
#pragma unroll
        for (int nt = 0; nt < 4; nt++) acc[mt][nt] = {0.f, 0.f, 0.f, 0.f};

    U8 wh[2][4], wl[2][4];
    float ax[2][2][8];

#define MG_LOADW(kk, buf) {                                                        \
    _Pragma("unroll")                                                              \
    for (int nt = 0; nt < 4; nt++) {                                               \
        int n = nb + nt * 16 + ln;                                                 \
        size_t off = ((size_t)(n * TKK + (kk)) * 4 + g) * 8;                       \
        *reinterpret_cast<uint4*>(&wh[buf][nt].u[0]) = *reinterpret_cast<const uint4*>(wpk + off); \
        *reinterpret_cast<uint4*>(&wl[buf][nt].u[0]) = *reinterpret_cast<const uint4*>(wlo + off); \
    } }

#define MG_LOADA(kk, buf) {                                                        \
    _Pragma("unroll")                                                              \
    for (int mt = 0; mt < 2; mt++) {                                               \
        float4 u0, u1;                                                             \
        if (MODE == MM_ARED) {                                                     \
            int gr = bm + mt * 16 + ln;                                            \
            int q = gr >> 3, b = gr & 7;                                           \
            int bh0 = (b << 3) + (kk);    /* h = kk: col block kk covers h=kk */   \
            size_t r0 = ((size_t)bh0 * 1000 + q) * 32;                             \
            const float* p0 = A + r0;                                              \
            const float* p1 = A + 2048000 + r0;                                    \
            float4 a0 = *reinterpret_cast<const float4*>(p0 + 4 * g);              \
            float4 c0 = *reinterpret_cast<const float4*>(p1 + 4 * g);              \
            float4 a1 = *reinterpret_cast<const float4*>(p0 + 16 + 4 * g);         \
            float4 c1 = *reinterpret_cast<const float4*>(p1 + 16 + 4 * g);         \
            float l = A2[(size_t)bh0 * 1000 + q] + A2[64000 + (size_t)bh0 * 1000 + q]; \
            float rl = 1.f / l;                                                    \
            u0.x = (a0.x + c0.x) * rl; u0.y = (a0.y + c0.y) * rl;                  \
            u0.z = (a0.z + c0.z) * rl; u0.w = (a0.w + c0.w) * rl;                  \
            u1.x = (a1.x + c1.x) * rl; u1.y = (a1.y + c1.y) * rl;                  \
            u1.z = (a1.z + c1.z) * rl; u1.w = (a1.w + c1.w) * rl;                  \
        } else {                                                                   \
            const float* ap = A + (size_t)(bm + mt * 16 + ln) * K + (kk) * 32 + 4 * g; \
            u0 = *reinterpret_cast<const float4*>(ap);                             \
            u1 = *reinterpret_cast<const float4*>(ap + 16);                        \
            if (MODE == MM_QKV && slab < 2) {                                      \
                const float* bp = A2 + (size_t)(bm + mt * 16 + ln) * K + (kk) * 32 + 4 * g; \
                float4 v0 = *reinterpret_cast<const float4*>(bp);                  \
                float4 v1 = *reinterpret_cast<const float4*>(bp + 16);             \
                u0.x += v0.x; u0.y += v0.y; u0.z += v0.z; u0.w += v0.w;            \
                u1.x += v1.x; u1.y += v1.y; u1.z += v1.z; u1.w += v1.w;            \
            }                                                                      \
        }                                                                          \
        ax[buf][mt][0] = u0.x; ax[buf][mt][1] = u0.y;                              \
        ax[buf][mt][2] = u0.z; ax[buf][mt][3] = u0.w;                              \
        ax[buf][mt][4] = u1.x; ax[buf][mt][5] = u1.y;                              \
        ax[buf][mt][6] = u1.z; ax[buf][mt][7] = u1.w;                              \
    } }

#define MG_STEP(buf) {                                                             \
    _Pragma("unroll")                                                              \
    for (int mt = 0; mt < 2; mt++) {                                               \
        U8 aH, aL;                                                                 \
        union { ushort s[8]; uint u[4]; } hs, ls;                                  \
        _Pragma("unroll")                                                          \
        for (int j = 0; j < 8; j++) split_bf(ax[buf][mt][j], hs.s[j], ls.s[j]);    \
        _Pragma("unroll")                                                          \
        for (int i = 0; i < 4; i++) { aH.u[i] = hs.u[i]; aL.u[i] = ls.u[i]; }      \
        _Pragma("unroll")                                                          \
        for (int nt = 0; nt < 4; nt++) {                                           \
            acc[mt][nt] = __builtin_amdgcn_mfma_f32_16x16x32_bf16(aL.v, wh[buf][nt].v, acc[mt][nt], 0, 0, 0); \
            acc[mt][nt] = __builtin_amdgcn_mfma_f32_16x16x32_bf16(aH.v, wl[buf][nt].v, acc[mt][nt], 0, 0, 0); \
            acc[mt][nt] = __builtin_amdgcn_mfma_f32_16x16x32_bf16(aH.v, wh[buf][nt].v, acc[mt][nt], 0, 0, 0); \
        }                                                                          \
    } }

    MG_LOADW(0, 0)
    MG_LOADA(0, 0)
#pragma unroll
    for (int kk = 0; kk < TKK; kk++) {
        if (kk + 1 < TKK) {
            MG_LOADW(kk + 1, (kk + 1) & 1)
            MG_LOADA(kk + 1, (kk + 1) & 1)
        }
        MG_STEP(kk & 1)
    }
#undef MG_LOADW
#undef MG_LOADA
#undef MG_STEP

#pragma unroll
    for (int nt = 0; nt < 4; nt++) {
        int n = nb + nt * 16 + ln;
        float bv = bias[n];
#pragma unroll
        for (int mt = 0; mt < 2; mt++) {
#pragma unroll
            for (int r = 0; r < 4; r++) {
                int gr = bm + mt * 16 + 4 * g + r;
                float val = acc[mt][nt][r] + bv;
                if (MODE == MM_QKV) {
                    int tok = gr >> 3, b = gr & 7;
                    int nloc = n & 255, h = nloc >> 5, d = nloc & 31;
                    if (slab == 0) val *= 0.17677669529663687f; // 1/sqrt(32)
                    ushort hs, ls;
                    split_bf(val, hs, ls);
                    if (slab < 2) {
                        // fragment-contiguous: slot(d) = ((d>>2)&3)*8 + (d&3) + 4*(d>>4)
                        int slot = ((d >> 2) & 3) * 8 + (d & 3) + 4 * (d >> 4);
                        ushort* base = (slab == 0) ? (ushort*)C0 : (ushort*)C1;
                        size_t off = ((size_t)(b * cHH + h) * 1024 + tok) * 32 + slot;
                        base[off]         = hs;
                        base[QKSZ2 + off] = ls;
                    } else {
                        // V: [bh][d][tokblk][slot], slot(o) over tok offset within 32-block
                        int o = tok & 31, kbi = tok >> 5;
                        int slot = ((o >> 2) & 3) * 8 + (o & 3) + 4 * (o >> 4);
                        ushort* vb = (ushort*)C2;
                        size_t off = ((size_t)(b * cHH + h) * 32 + d) * 1024 + kbi * 32 + slot;
                        vb[off]         = hs;
                        vb[QKSZ2 + off] = ls;
                    }
                } else if (MODE == MM_OPROJ) {
                    int b = gr / cNQ, q = gr - b * cNQ;
                    ((float*)C0)[((size_t)q * cBS + b) * cE + n] = val;
                } else {
                    if (MODE == MM_RELU) val = fmaxf(val, 0.f);
                    ((float*)C0)[(size_t)gr * NFULL + n] = val;
                }
            }
        }
    }
}

// ---------------------------------------------------------------- MFMA flash attention (v8: 2x Q-blocking, XCD swizzle, K-split)
__global__ __launch_bounds__(256) void k_attn3(
    const ushort* __restrict__ qhi, const ushort* __restrict__ qlo,
    const ushort* __restrict__ khi, const ushort* __restrict__ klo,
    const ushort* __restrict__ vhi, const ushort* __restrict__ vlo,
    float* __restrict__ po, float* __restrict__ plsum)
{
    const int bid   = blockIdx.x;           // 1024 blocks
    const int xcd   = bid & 7;
    const int inner = bid >> 3;             // 0..127
    const int bh    = ((inner & 7) << 3) + xcd;   // bh % 8 == bid % 8
    const int rest  = inner >> 3;           // 0..15
    const int qbix  = rest & 7;             // q-block of 128 rows
    const int z     = rest >> 3;            // 0..1

    const int w    = threadIdx.x >> 6;
    const int lane = threadIdx.x & 63;
    const int g    = lane >> 4;
    const int ql   = lane & 15;
    const int qA   = qbix * 128 + w * 32;   // wave: rows [qA, qA+16) and [qA+16, qA+32)

    const size_t qoffA = ((size_t)bh * 1024 + qA + ql) * 32 + g * 8;
    U8 bQAh, bQAl, bQBh, bQBl;
    *reinterpret_cast<uint4*>(&bQAh.u[0]) = *reinterpret_cast<const uint4*>(qhi + qoffA);
    *reinterpret_cast<uint4*>(&bQAl.u[0]) = *reinterpret_cast<const uint4*>(qlo + qoffA);
    *reinterpret_cast<uint4*>(&bQBh.u[0]) = *reinterpret_cast<const uint4*>(qhi + qoffA + 16 * 32);
    *reinterpret_cast<uint4*>(&bQBl.u[0]) = *reinterpret_cast<const uint4*>(qlo + qoffA + 16 * 32);
    const size_t koff = ((size_t)bh * 1024 + ql) * 32 + g * 8;
    const size_t voff = ((size_t)bh * 32 + ql) * 1024 + g * 8;

    f32x4 oA0 = {0.f,0.f,0.f,0.f}, oA1 = {0.f,0.f,0.f,0.f};
    f32x4 oB0 = {0.f,0.f,0.f,0.f}, oB1 = {0.f,0.f,0.f,0.f};
    float lpartA = 0.f, lpartB = 0.f;
    const f32x4 zz = {0.f, 0.f, 0.f, 0.f};

    const int kt0 = z * 16;
#pragma unroll
    for (int kti = 0; kti < 16; kti++) {
        const int kt = kt0 + kti;
        U8 k0h, k1h, k0l, k1l, v0h, v1h, v0l, v1l;
        {
            size_t kb32 = (size_t)kt * 32 * 32;
            *reinterpret_cast<uint4*>(&k0h.u[0]) = *reinterpret_cast<const uint4*>(khi + koff + kb32);
            *reinterpret_cast<uint4*>(&k1h.u[0]) = *reinterpret_cast<const uint4*>(khi + koff + kb32 + 512);
            *reinterpret_cast<uint4*>(&k0l.u[0]) = *reinterpret_cast<const uint4*>(klo + koff + kb32);
            *reinterpret_cast<uint4*>(&k1l.u[0]) = *reinterpret_cast<const uint4*>(klo + koff + kb32 + 512);
            size_t vb32 = voff + (size_t)kt * 32;
            *reinterpret_cast<uint4*>(&v0h.u[0]) = *reinterpret_cast<const uint4*>(vhi + vb32);
            *reinterpret_cast<uint4*>(&v1h.u[0]) = *reinterpret_cast<const uint4*>(vhi + vb32 + 16 * 1024);
            *reinterpret_cast<uint4*>(&v0l.u[0]) = *reinterpret_cast<const uint4*>(vlo + vb32);
            *reinterpret_cast<uint4*>(&v1l.u[0]) = *reinterpret_cast<const uint4*>(vlo + vb32 + 16 * 1024);
        }

        const bool tail = (kti == 15) && (z == 1);

        f32x4 sA0 = __builtin_amdgcn_mfma_f32_16x16x32_bf16(k0l.v, bQAh.v, zz, 0, 0, 0);
        sA0 = __builtin_amdgcn_mfma_f32_16x16x32_bf16(k0h.v, bQAl.v, sA0, 0, 0, 0);
        sA0 = __builtin_amdgcn_mfma_f32_16x16x32_bf16(k0h.v, bQAh.v, sA0, 0, 0, 0);
        f32x4 sB0 = __builtin_amdgcn_mfma_f32_16x16x32_bf16(k0l.v, bQBh.v, zz, 0, 0, 0);
        sB0 = __builtin_amdgcn_mfma_f32_16x16x32_bf16(k0h.v, bQBl.v, sB0, 0, 0, 0);
        sB0 = __builtin_amdgcn_mfma_f32_16x16x32_bf16(k0h.v, bQBh.v, sB0, 0, 0, 0);
        f32x4 sA1, sB1;
        if (tail) {
            int tb = 31 * 32 + 4 * g;
#pragma unroll
            for (int r = 0; r < 4; r++) {
                if (tb + r >= cNQ) { sA0[r] = -INFINITY; sB0[r] = -INFINITY; }
            }
            sA1[0] = sA1[1] = sA1[2] = sA1[3] = -INFINITY;
            sB1[0] = sB1[1] = sB1[2] = sB1[3] = -INFINITY;
        } else {
            sA1 = __builtin_amdgcn_mfma_f32_16x16x32_bf16(k1l.v, bQAh.v, zz, 0, 0, 0);
            sA1 = __builtin_amdgcn_mfma_f32_16x16x32_bf16(k1h.v, bQAl.v, sA1, 0, 0, 0);
            sA1 = __builtin_amdgcn_mfma_f32_16x16x32_bf16(k1h.v, bQAh.v, sA1, 0, 0, 0);
            sB1 = __builtin_amdgcn_mfma_f32_16x16x32_bf16(k1l.v, bQBh.v, zz, 0, 0, 0);
            sB1 = __builtin_amdgcn_mfma_f32_16x16x32_bf16(k1h.v, bQBl.v, sB1, 0, 0, 0);
            sB1 = __builtin_amdgcn_mfma_f32_16x16x32_bf16(k1h.v, bQBh.v, sB1, 0, 0, 0);
        }

        float pA00 = __expf(sA0[0]), pA01 = __expf(sA0[1]);
        float pA02 = __expf(sA0[2]), pA03 = __expf(sA0[3]);
        float pA10 = __expf(sA1[0]), pA11 = __expf(sA1[1]);
        float pA12 = __expf(sA1[2]), pA13 = __expf(sA1[3]);
        lpartA += ((pA00 + pA01) + (pA02 + pA03)) + ((pA10 + pA11) + (pA12 + pA13));
        float pB00 = __expf(sB0[0]), pB01 = __expf(sB0[1]);
        float pB02 = __expf(sB0[2]), pB03 = __expf(sB0[3]);
        float pB10 = __expf(sB1[0]), pB11 = __expf(sB1[1]);
        float pB12 = __expf(sB1[2]), pB13 = __expf(sB1[3]);
        lpartB += ((pB00 + pB01) + (pB02 + pB03)) + ((pB10 + pB11) + (pB12 + pB13));

        U8 fpAh, fpAl, fpBh, fpBl;
        pk_split2(pA00, pA01, fpAh.u[0], fpAl.u[0]);
        pk_split2(pA02, pA03, fpAh.u[1], fpAl.u[1]);
        pk_split2(pA10, pA11, fpAh.u[2], fpAl.u[2]);
        pk_split2(pA12, pA13, fpAh.u[3], fpAl.u[3]);
        pk_split2(pB00, pB01, fpBh.u[0], fpBl.u[0]);
        pk_split2(pB02, pB03, fpBh.u[1], fpBl.u[1]);
        pk_split2(pB10, pB11, fpBh.u[2], fpBl.u[2]);
        pk_split2(pB12, pB13, fpBh.u[3], fpBl.u[3]);

        oA0 = __builtin_amdgcn_mfma_f32_16x16x32_bf16(v0l.v, fpAh.v, oA0, 0, 0, 0);
        oA0 = __builtin_amdgcn_mfma_f32_16x16x32_bf16(v0h.v, fpAl.v, oA0, 0, 0, 0);
        oA0 = __builtin_amdgcn_mfma_f32_16x16x32_bf16(v0h.v, fpAh.v, oA0, 0, 0, 0);
        oA1 = __builtin_amdgcn_mfma_f32_16x16x32_bf16(v1l.v, fpAh.v, oA1, 0, 0, 0);
        oA1 = __builtin_amdgcn_mfma_f32_16x16x32_bf16(v1h.v, fpAl.v, oA1, 0, 0, 0);
        oA1 = __builtin_amdgcn_mfma_f32_16x16x32_bf16(v1h.v, fpAh.v, oA1, 0, 0, 0);
        oB0 = __builtin_amdgcn_mfma_f32_16x16x32_bf16(v0l.v, fpBh.v, oB0, 0, 0, 0);
        oB0 = __builtin_amdgcn_mfma_f32_16x16x32_bf16(v0h.v, fpBl.v, oB0, 0, 0, 0);
        oB0 = __builtin_amdgcn_mfma_f32_16x16x32_bf16(v0h.v, fpBh.v, oB0, 0, 0, 0);
        oB1 = __builtin_amdgcn_mfma_f32_16x16x32_bf16(v1l.v, fpBh.v, oB1, 0, 0, 0);
        oB1 = __builtin_amdgcn_mfma_f32_16x16x32_bf16(v1h.v, fpBl.v, oB1, 0, 0, 0);
        oB1 = __builtin_amdgcn_mfma_f32_16x16x32_bf16(v1h.v, fpBh.v, oB1, 0, 0, 0);
    }

    // per-lane partial denominators -> per-q via 2 xor-shfls (same q across g groups)
    float lsumA = lpartA;
    lsumA += __shfl_xor(lsumA, 16, 64);
    lsumA += __shfl_xor(lsumA, 32, 64);
    float lsumB = lpartB;
    lsumB += __shfl_xor(lsumB, 16, 64);
    lsumB += __shfl_xor(lsumB, 32, 64);

    {
        const int q = qA + ql;
        if (q < cNQ) {
            size_t base = ((size_t)(z * 64 + bh) * 1000 + q) * 32;
            float4 v0, v1;
            v0.x = oA0[0]; v0.y = oA0[1]; v0.z = oA0[2]; v0.w = oA0[3];
            v1.x = oA1[0]; v1.y = oA1[1]; v1.z = oA1[2]; v1.w = oA1[3];
            *reinterpret_cast<float4*>(po + base + 4 * g)      = v0;
            *reinterpret_cast<float4*>(po + base + 16 + 4 * g) = v1;
            if (g == 0) plsum[(size_t)(z * 64 + bh) * 1000 + q] = lsumA;
        }
    }
    {
        const int q = qA + 16 + ql;
        if (q < cNQ) {
            size_t base = ((size_t)(z * 64 + bh) * 1000 + q) * 32;
            float4 v0, v1;
            v0.x = oB0[0]; v0.y = oB0[1]; v0.z = oB0[2]; v0.w = oB0[3];
            v1.x = oB1[0]; v1.y = oB1[1]; v1.z = oB1[2]; v1.w = oB1[3];
            *reinterpret_cast<float4*>(po + base + 4 * g)      = v0;
            *reinterpret_cast<float4*>(po + base + 16 + 4 * g) = v1;
            if (g == 0) plsum[(size_t)(z * 64 + bh) * 1000 + q] = lsumB;
        }
    }
}

// ---------------------------------------------------------------- layernorm
__global__ __launch_bounds__(256) void k_ln(
    const float* __restrict__ a, const float* __restrict__ b,
    const float* __restrict__ w, const float* __restrict__ bias,
    const float* __restrict__ addc,
    float* __restrict__ outp, float* __restrict__ out2)
{
    int rrow = blockIdx.x, t = threadIdx.x;
    size_t base = (size_t)rrow * cE;
    float v = a[base + t] + b[base + t];
    float s = v;
#pragma unroll
    for (int off = 32; off > 0; off >>= 1) s += __shfl_down(s, off, 64);
    __shared__ float red1[4], red2[4];
    int wid = t >> 6, lane = t & 63;
    if (lane == 0) red1[wid] = s;
    __syncthreads();
    float mu = (red1[0] + red1[1] + red1[2] + red1[3]) * (1.f / cE);
    float e = v - mu;
    float s2 = e * e;
#pragma unroll
    for (int off = 32; off > 0; off >>= 1) s2 += __shfl_down(s2, off, 64);
    if (lane == 0) red2[wid] = s2;
    __syncthreads();
    float var = (red2[0] + red2[1] + red2[2] + red2[3]) * (1.f / cE);
    float y = e * (1.f / sqrtf(var + 1e-5f)) * w[t] + bias[t];
    outp[base + t] = y;
    if (out2 != nullptr) out2[base + t] = y + addc[base + t];
}

// ---------------------------------------------------------------- MSDA sampling (vimg row-major [tok][E], tok = nv*BS + b)
__device__ __forceinline__ float samp_one(const float* __restrict__ img, int x, int y)
{
    bool ok = (x >= 0) & (x < cW) & (y >= 0) & (y < cH);
    int xc = min(max(x, 0), cW - 1);
    int yc = min(max(y, 0), cH - 1);
    float v = img[(size_t)(yc * cW + xc) * (cBS * cE)];
    return ok ? v : 0.f;
}

__global__ __launch_bounds__(256) void k_msda(
    const float* __restrict__ vimg, const float* __restrict__ loc,
    const float* __restrict__ aw, float* __restrict__ msp)
{
    int gid = blockIdx.x * 256 + threadIdx.x;
    int d  = gid & 31;
    int h  = (gid >> 5) & 7;
    int bq = gid >> 8;
    int b  = bq / cNQ;
    const float* lp = loc + ((size_t)bq * cHH + h) * (cP * 2);
    const float* ap = aw + ((size_t)bq * cHH + h) * cP;
    const float* img = vimg + (size_t)b * cE + h * cDH + d;
    float acc = 0.f;
#pragma unroll
    for (int p = 0; p < cP; p++) {
        float g0 = 2.f * lp[p * 2 + 0] - 1.f;
        float g1 = 2.f * lp[p * 2 + 1] - 1.f;
        float xf = (g0 + 1.f) * 0.5f * (float)cW - 0.5f;
        float yf = (g1 + 1.f) * 0.5f * (float)cH - 0.5f;
        float x0f = floorf(xf), y0f = floorf(yf);
        float wx = xf - x0f, wy = yf - y0f;
        int x0 = (int)x0f, y0 = (int)y0f;
        float v00 = samp_one(img, x0,     y0);
        float v01 = samp_one(img, x0 + 1, y0);
        float v10 = samp_one(img, x0,     y0 + 1);
        float v11 = samp_one(img, x0 + 1, y0 + 1);
        float bil = v00 * (1.f - wx) * (1.f - wy) + v01 * wx * (1.f - wy)
                  + v10 * (1.f - wx) * wy        + v11 * wx * wy;
        acc = fmaf(bil, ap[p], acc);
    }
    msp[gid] = acc;
}

// ---------------------------------------------------------------- launch
extern "C" void kernel_launch(void* const* d_in, const int* in_sizes, int n_in,
                              void* d_out, int out_size, void* d_ws, size_t ws_size,
                              hipStream_t stream)
{
    const float* query = (const float*)d_in[0];
    const float* qpos  = (const float*)d_in[1];
    const float* value = (const float*)d_in[2];
    const float* refp  = (const float*)d_in[3];
    const float* inw   = (const float*)d_in[4];
    const float* inb   = (const float*)d_in[5];
    const float* outw  = (const float*)d_in[6];
    const float* outb  = (const float*)d_in[7];
    const float* ln1w  = (const float*)d_in[8];
    const float* ln1b  = (const float*)d_in[9];
    const float* ln2w  = (const float*)d_in[10];
    const float* ln2b  = (const float*)d_in[11];
    const float* ln3w  = (const float*)d_in[12];
    const float* ln3b  = (const float*)d_in[13];
    const float* offw  = (const float*)d_in[14];
    const float* offb  = (const float*)d_in[15];
    const float* aww   = (const float*)d_in[16];
    const float* awbias= (const float*)d_in[17];
    const float* vpw   = (const float*)d_in[18];
    const float* vpb   = (const float*)d_in[19];
    const float* opw   = (const float*)d_in[20];
    const float* opb   = (const float*)d_in[21];
    const float* f1w   = (const float*)d_in[22];
    const float* f1b   = (const float*)d_in[23];
    const float* f2w   = (const float*)d_in[24];
    const float* f2b   = (const float*)d_in[25];
    float* out = (float*)d_out;

    float* ws = (float*)d_ws;
    const size_t S = (size_t)NTOK * cE;              // 2,048,000 floats
    const size_t BPADF = 6 * QKSZ2 / 2;              // 6,291,456 floats
    const size_t WPKF = 655360 + 24576;              // packed weights
    const size_t PLS  = 128000;                      // plsum[2][64][1000]
    const size_t need = 2 * S + BPADF + 512000 + 256000 + WPKF + PLS + (size_t)cBS * cHH * cNV * cDH;
    if (ws_size < need * sizeof(float)) return;

    float* P0   = ws;
    float* P1   = ws + S;
    float* Bpad = ws + 2 * S;
    float* locb = Bpad + BPADF;
    float* awb2 = locb + 512000;
    float* wpkf = awb2 + 256000;
    float* plsb = wpkf + WPKF;
    float* vimg = plsb + PLS;

    ushort* qhi = (ushort*)Bpad;
    ushort* qlo = qhi + QKSZ2;
    ushort* khi = qhi + 2 * QKSZ2;
    ushort* klo = qhi + 3 * QKSZ2;
    ushort* vhi = qhi + 4 * QKSZ2;
    ushort* vlo = qhi + 5 * QKSZ2;

    ushort* wpk_vp = (ushort*)wpkf;            // 131072 (wave-contiguous: hi 65536 + lo)
    ushort* wpk_in = wpk_vp + 131072;          // 393216
    ushort* wpk_ou = wpk_in + 393216;          // 131072
    ushort* wpk_op = wpk_ou + 131072;          // 131072
    ushort* wpk_f1 = wpk_op + 131072;          // 262144
    ushort* wpk_f2 = wpk_f1 + 262144;          // 262144
    ushort* wpk_oa = wpk_f2 + 262144;          // 49152 (96 rows: hi 24576 + lo)

    // pack weights
    k_prepw2<<<dim3(32), dim3(256), 0, stream>>>(vpw, wpk_vp);
    k_prepw<<<dim3(96), dim3(256), 0, stream>>>(inw,  wpk_in, 8,  24576, 196608);
    k_prepw<<<dim3(32), dim3(256), 0, stream>>>(outw, wpk_ou, 8,  8192,  65536);
    k_prepw<<<dim3(32), dim3(256), 0, stream>>>(opw,  wpk_op, 8,  8192,  65536);
    k_prepw<<<dim3(64), dim3(256), 0, stream>>>(f1w,  wpk_f1, 8,  16384, 131072);
    k_prepw<<<dim3(64), dim3(256), 0, stream>>>(f2w,  wpk_f2, 16, 16384, 131072);
    k_prepw<<<dim3(8),  dim3(256), 0, stream>>>(offw, wpk_oa, 8,  2048,  24576);
    k_prepw<<<dim3(4),  dim3(256), 0, stream>>>(aww,  wpk_oa + 16384, 8, 1024, 24576);

    // value projection: fused gload_lds-pipelined split + MFMA GEMM, float4 C-writes
    k_bgemm2<<<dim3(2500), dim3(256), 0, stream>>>(value, wpk_vp, vpb, vimg);

    // zero V pad tail only (kbi=31 blocks; unwritten slots must be finite; 0*p=0)
    k_zerovpad<<<dim3(16), dim3(256), 0, stream>>>(vhi);

    // QKV projection (q,k from query+qpos fused; v from query) -> fragment-contiguous bf16 hi/lo
    k_mgemm<MM_QKV, 8, 768><<<dim3(250, 3), dim3(256), 0, stream>>>(
        query, qpos, wpk_in, 196608, inb, qhi, khi, vhi);

    // split-precision MFMA flash attention, 2x Q-blocked, 2-way K-split, XCD-swizzled
    k_attn3<<<dim3(1024), dim3(256), 0, stream>>>(
        qhi, qlo, khi, klo, vhi, vlo, P0, plsb);

    // fused combine + out-proj: reads po partials + plsum directly (k_ared deleted)
    float* mha_y = P1;
    k_mgemm<MM_ARED, 8, 256><<<dim3(250, 1), dim3(256), 0, stream>>>(
        P0, plsb, wpk_ou, 65536, outb, mha_y, nullptr, nullptr);

    // LN1: x = LN(query + mha_y), xq = x + query_pos
    float* x  = Bpad;
    float* xq = Bpad + S;
    k_ln<<<dim3(NTOK), dim3(256), 0, stream>>>(query, mha_y, ln1w, ln1b, qpos, x, xq);

    // off/aw head: GEMM (raw = xq @ Wcat^T) + loc/softmax postprocess
    float* rawb = P0;
    k_oagemm<<<dim3(125), dim3(256), 0, stream>>>(xq, wpk_oa, rawb);
    k_locaw<<<dim3((NTOK * 96 + 255) / 256), dim3(256), 0, stream>>>(
        rawb, offb, awbias, refp, locb, awb2);

    // MSDA bilinear sample
    float* ms_pre = P1;
    k_msda<<<dim3(NTOK * cE / 256), dim3(256), 0, stream>>>(vimg, locb, awb2, ms_pre);

    // oproj (rows (b,q) -> write (q,b))
    float* ms_y = P0;
    k_mgemm<MM_OPROJ, 8, 256><<<dim3(250, 1), dim3(256), 0, stream>>>(
        ms_pre, nullptr, wpk_op, 65536, opb, ms_y, nullptr, nullptr);

    // LN2: x2 = LN(x + ms_y)
    float* x2 = Bpad + 2 * S;
    k_ln<<<dim3(NTOK), dim3(256), 0, stream>>>(x, ms_y, ln2w, ln2b, nullptr, x2, nullptr);

    // FFN (hbuf reuses Bpad[0..2S) — x/xq dead)
    float* hbuf = Bpad;
    k_mgemm<MM_RELU, 8, 512><<<dim3(250, 2), dim3(256), 0, stream>>>(
        x2, nullptr, wpk_f1, 131072, f1b, hbuf, nullptr, nullptr);
    float* y3 = P0;
    k_mgemm<MM_PLAIN, 16, 256><<<dim3(250, 1), dim3(256), 0, stream>>>(
        hbuf, nullptr, wpk_f2, 131072, f2b, y3, nullptr, nullptr);

    // LN3 -> out
    k_ln<<<dim3(NTOK), dim3(256), 0, stream>>>(x2, y3, ln3w, ln3b, nullptr, out, nullptr);
}